// Round 7
// baseline (654.644 us; speedup 1.0000x reference)
//
#include <hip/hip_runtime.h>
#include <hip/hip_bf16.h>
#include <hip/hip_cooperative_groups.h>

namespace cg = cooperative_groups;

// Problem constants (match reference)
#define DD 128      // feature dim
#define AA 4        // edge attr dim
#define HH 2        // heads

typedef short short8 __attribute__((ext_vector_type(8)));
typedef float f32x4 __attribute__((ext_vector_type(4)));

// bf16 pack/unpack (RNE)
__device__ inline unsigned short f2bf(float f) {
    unsigned u = __float_as_uint(f);
    unsigned r = (u + 0x7fffu + ((u >> 16) & 1u)) >> 16;
    return (unsigned short)r;
}
__device__ inline float4 unpack_bf16x4(uint2 v) {
    float4 r;
    r.x = __uint_as_float(v.x << 16);
    r.y = __uint_as_float(v.x & 0xffff0000u);
    r.z = __uint_as_float(v.y << 16);
    r.w = __uint_as_float(v.y & 0xffff0000u);
    return r;
}
__device__ inline uint2 pack_bf16x4(float a, float b, float c, float d) {
    uint2 p;
    p.x = (unsigned)f2bf(a) | ((unsigned)f2bf(b) << 16);
    p.y = (unsigned)f2bf(c) | ((unsigned)f2bf(d) << 16);
    return p;
}

// ---------------------------------------------------------------------------
// Cooperative CSR build: zero + histogram + scan + scatter in ONE kernel.
// 256 blocks x 256 threads (all co-resident). Also initializes y = fb.
// row_off[N] = E (known a priori).
// ---------------------------------------------------------------------------

__global__ __launch_bounds__(256) void csr_coop(const int* __restrict__ src,
                                                const int* __restrict__ dst,
                                                int* __restrict__ cnt,
                                                int* __restrict__ row_off,
                                                int* __restrict__ cursor,
                                                int* __restrict__ csr_src,
                                                int* __restrict__ csr_eid,
                                                int* __restrict__ bsum,
                                                float* __restrict__ y,
                                                const float* __restrict__ fb,
                                                int E, int N) {
    cg::grid_group grid = cg::this_grid();
    int t = threadIdx.x;
    int gt = blockIdx.x * 256 + t;
    const int GT = gridDim.x * 256;   // 65536 >= N
    int lane = t & 63, w = t >> 6;
    __shared__ int wsum[4];
    __shared__ int ws2[4];

    // phase 0: zero counters, init y
    for (int i = gt; i < N; i += GT) cnt[i] = 0;
    if (gt < 128) y[gt] = fb[0];
    grid.sync();

    // phase 1: histogram of dst
    for (int e = gt; e < E; e += GT) atomicAdd(&cnt[dst[e]], 1);
    grid.sync();

    // phase 2a: block-local inclusive scan (each block owns 256 contiguous)
    int v = (gt < N) ? cnt[gt] : 0;
    int x = v;
    #pragma unroll
    for (int o = 1; o < 64; o <<= 1) {
        int u = __shfl_up(x, o);
        if (lane >= o) x += u;
    }
    if (lane == 63) wsum[w] = x;
    __syncthreads();
    int woff = 0;
    for (int i = 0; i < w; ++i) woff += wsum[i];
    int incl = x + woff;
    int btot = wsum[0] + wsum[1] + wsum[2] + wsum[3];
    if (t == 0) bsum[blockIdx.x] = btot;
    grid.sync();

    // phase 2b: block 0 exclusive-scans the 256 block sums
    if (blockIdx.x == 0) {
        int bv = bsum[t];
        int bx = bv;
        #pragma unroll
        for (int o = 1; o < 64; o <<= 1) {
            int u = __shfl_up(bx, o);
            if (lane >= o) bx += u;
        }
        if (lane == 63) ws2[w] = bx;
        __syncthreads();
        int wo = 0;
        for (int i = 0; i < w; ++i) wo += ws2[i];
        bsum[t] = bx + wo - bv;    // exclusive prefix
    }
    grid.sync();

    // phase 2c: final exclusive prefix per element
    int base = bsum[blockIdx.x];
    int ex = base + incl - v;
    if (gt < N) { row_off[gt] = ex; cursor[gt] = ex; }
    if (gt == 0) row_off[N] = E;
    grid.sync();

    // phase 3: scatter into CSR order
    for (int e = gt; e < E; e += GT) {
        int p = atomicAdd(&cursor[dst[e]], 1);
        csr_src[p] = src[e];
        csr_eid[p] = e;
    }
}

// ---------------------------------------------------------------------------
// Fragment-shuffled operand packing for MFMA GEMM.
// A_shuf (bf16): cell(g,ks,q,m) = short8 of A[row=g*16+m][k=ks*32+q*8 .. +8]
//   flat short8 idx = ((g*4+ks)*4+q)*16 + m
// B_shuf (bf16): cell(ct,ks,q,n) = short8 of W[k=ks*32+q*8 .. +8][col=ct*16+n]
//   flat short8 idx = ((ct*4+ks)*4+q)*16 + n
// ---------------------------------------------------------------------------

__global__ __launch_bounds__(256) void pack_a0(const float* __restrict__ X,
                                               uint2* __restrict__ As, int N) {
    int t = blockIdx.x * blockDim.x + threadIdx.x;
    if (t >= N * 32) return;
    int r = t >> 5, kq4 = t & 31;
    float4 v = ((const float4*)X)[t];
    int g = r >> 4, m = r & 15;
    int ks = kq4 >> 3, q = (kq4 >> 1) & 3;
    int cell = ((g * 4 + ks) * 4 + q) * 16 + m;
    As[cell * 2 + (kq4 & 1)] = pack_bf16x4(v.x, v.y, v.z, v.w);
}

__global__ __launch_bounds__(256) void pack_w3(const float* __restrict__ W0,
                                               const float* __restrict__ W1,
                                               const float* __restrict__ W2,
                                               unsigned short* __restrict__ Bs) {
    int t = blockIdx.x * blockDim.x + threadIdx.x;
    if (t >= 3 * 128 * 64) return;
    int l = t / (128 * 64);
    int r = t - l * (128 * 64);
    const float* W = (l == 0) ? W0 : (l == 1) ? W1 : W2;
    unsigned short* B = Bs + (size_t)l * 128 * 256;
    int k = r >> 6, c4g = r & 63;
    float4 v = ((const float4*)W)[r];
    int ct = c4g >> 2, n0 = (c4g & 3) * 4;
    int ks = k >> 5, q = (k >> 3) & 3, j = k & 7;
    int cellbase = ((ct * 4 + ks) * 4 + q) * 16 + n0;
    B[(cellbase + 0) * 8 + j] = f2bf(v.x);
    B[(cellbase + 1) * 8 + j] = f2bf(v.y);
    B[(cellbase + 2) * 8 + j] = f2bf(v.z);
    B[(cellbase + 3) * 8 + j] = f2bf(v.w);
}

// ---------------------------------------------------------------------------
// MFMA GEMM + fused epilogue. One wave per (16-row group, head-half):
// 8 col-tiles of 16; K=128 in 4 steps of 32. Emits bf16 xhb (LDS transpose,
// wave-private -> no barrier) and this half's attention logits.
// ---------------------------------------------------------------------------

__global__ __launch_bounds__(256) void gemm_mfma(const short8* __restrict__ As,
                                                 const short8* __restrict__ Bs,
                                                 const float* __restrict__ bias,
                                                 const float* __restrict__ att,
                                                 uint2* __restrict__ xhb,
                                                 float* __restrict__ aiaj, int Ngroups) {
    __shared__ __align__(16) unsigned short sh[4][16 * 132];
    int w = threadIdx.x >> 6;
    int flat = blockIdx.x * 4 + w;
    int wid = flat >> 1, half = flat & 1;
    int lane = threadIdx.x & 63;
    if (wid >= Ngroups) return;
    int q = lane >> 4, m = lane & 15;

    const short8* Ag = As + (size_t)wid * 256;
    f32x4 acc[8];
    #pragma unroll
    for (int c8 = 0; c8 < 8; ++c8) acc[c8] = (f32x4){0.f, 0.f, 0.f, 0.f};

    #pragma unroll
    for (int ks = 0; ks < 4; ++ks) {
        short8 a = Ag[ks * 64 + lane];
        #pragma unroll
        for (int c8 = 0; c8 < 8; ++c8) {
            short8 b = Bs[(half * 8 + c8) * 256 + ks * 64 + lane];
            acc[c8] = __builtin_amdgcn_mfma_f32_16x16x32_bf16(a, b, acc[c8], 0, 0, 0);
        }
    }

    // Epilogue. C/D layout: col(local) = c8*16+m, row(local) = q*4+reg.
    const float* atth = att + half * (2 * DD + AA);
    float ai[4] = {}, aj[4] = {};
    #pragma unroll
    for (int c8 = 0; c8 < 8; ++c8) {
        int col = c8 * 16 + m;
        float aS = atth[col];
        float aD = atth[DD + col];
        float bv = bias[(half * 8 + c8) * 16 + m];
        #pragma unroll
        for (int reg = 0; reg < 4; ++reg) {
            float val = acc[c8][reg] + bv;
            sh[w][(q * 4 + reg) * 132 + col] = f2bf(val);
            ai[reg] += val * aS;
            aj[reg] += val * aD;
        }
    }
    #pragma unroll
    for (int o = 1; o < 16; o <<= 1) {
        #pragma unroll
        for (int reg = 0; reg < 4; ++reg) {
            ai[reg] += __shfl_xor(ai[reg], o);
            aj[reg] += __shfl_xor(aj[reg], o);
        }
    }
    if (m == 0) {
        #pragma unroll
        for (int reg = 0; reg < 4; ++reg) {
            int row = wid * 16 + q * 4 + reg;
            aiaj[row * 4 + half] = ai[reg];
            aiaj[row * 4 + 2 + half] = aj[reg];
        }
    }
    // wave-private LDS tile -> coalesced bf16 store (2 rows per inst)
    #pragma unroll
    for (int r2 = 0; r2 < 8; ++r2) {
        int row = r2 * 2 + (lane >> 5);
        uint2 v = *(const uint2*)&sh[w][row * 132 + (lane & 31) * 4];
        xhb[(size_t)(wid * 16 + row) * 64 + half * 32 + (lane & 31)] = v;
    }
}

// ---------------------------------------------------------------------------
// Fused edge transform for ALL 3 layers, CSR-ordered (coalesced writes,
// one random 16B read per edge).
// ---------------------------------------------------------------------------

__device__ inline void edge_stage(const float4& ev, const float* __restrict__ linE,
                                  const float* __restrict__ att, float2& ae, float4& enext) {
    float eh[8];
    #pragma unroll
    for (int c = 0; c < 8; ++c)
        eh[c] = ev.x * linE[c] + ev.y * linE[8 + c] + ev.z * linE[16 + c] + ev.w * linE[24 + c];
    float a0 = 0.f, a1 = 0.f;
    #pragma unroll
    for (int a = 0; a < 4; ++a) {
        a0 += eh[a]     * att[2 * DD + a];
        a1 += eh[4 + a] * att[(2 * DD + AA) + 2 * DD + a];
    }
    ae.x = a0; ae.y = a1;
    enext.x = fmaxf(0.5f * (eh[0] + eh[4]), 0.f);
    enext.y = fmaxf(0.5f * (eh[1] + eh[5]), 0.f);
    enext.z = fmaxf(0.5f * (eh[2] + eh[6]), 0.f);
    enext.w = fmaxf(0.5f * (eh[3] + eh[7]), 0.f);
}

__global__ __launch_bounds__(256) void edge_all(const float* __restrict__ ein,
                                                const float* __restrict__ linE0, const float* __restrict__ att0,
                                                const float* __restrict__ linE1, const float* __restrict__ att1,
                                                const float* __restrict__ linE2, const float* __restrict__ att2,
                                                const int* __restrict__ csr_eid,
                                                float2* __restrict__ ae0,
                                                float2* __restrict__ ae1,
                                                float2* __restrict__ ae2, int E) {
    int p = blockIdx.x * blockDim.x + threadIdx.x;
    if (p >= E) return;
    int eid = csr_eid[p];
    float4 ev = ((const float4*)ein)[eid];
    float2 ae; float4 en;
    edge_stage(ev, linE0, att0, ae, en); ae0[p] = ae;
    edge_stage(en, linE1, att1, ae, ev); ae1[p] = ae;
    edge_stage(ev, linE2, att2, ae, en); ae2[p] = ae;
}

// ---------------------------------------------------------------------------
// Aggregation: one wave per dst node, BARRIER-FREE (single-wave block; LDS
// RAW within a wave is ordered by lgkmcnt). Single-pass softmax (shift-
// invariant, logits O(10)). bf16 gather payload; bf16 skip.
// ---------------------------------------------------------------------------

__global__ __launch_bounds__(64) void aggregate(const uint2* __restrict__ xhb,
                                                const float* __restrict__ aiaj,
                                                const float2* __restrict__ ae,
                                                const int* __restrict__ row_off,
                                                const int* __restrict__ csr_src,
                                                uint2* __restrict__ hshuf,
                                                const float* __restrict__ fw,
                                                float* __restrict__ pdots, int N) {
    int d = blockIdx.x;
    int lane = threadIdx.x;
    int s0 = row_off[d], s1 = row_off[d + 1];
    int deg = s1 - s0;
    const float2* aiaj2 = (const float2*)aiaj;
    float2 ajv = aiaj2[d * 2 + 1];   // (aj0, aj1)

    __shared__ float lex[64][2];
    __shared__ int lsrc[64];
    float4 acc = {0.f, 0.f, 0.f, 0.f};
    float den0 = 0.f, den1 = 0.f;
    int head = lane >> 5;

    for (int c = 0; c < deg; c += 64) {
        int n = min(64, deg - c);
        if (lane < n) {
            int p = s0 + c + lane;
            int s = csr_src[p];
            float2 aiv = aiaj2[s * 2];
            float2 aev = ae[p];
            float a0 = aiv.x + ajv.x + aev.x; a0 = a0 > 0.f ? a0 : 0.2f * a0;
            float a1 = aiv.y + ajv.y + aev.y; a1 = a1 > 0.f ? a1 : 0.2f * a1;
            float e0 = __expf(a0), e1 = __expf(a1);
            den0 += e0; den1 += e1;
            lex[lane][0] = e0; lex[lane][1] = e1;
            lsrc[lane] = s;
        }
        #pragma unroll 4
        for (int j = 0; j < n; ++j) {
            float wgt = lex[j][head];
            float4 xv = unpack_bf16x4(xhb[(size_t)lsrc[j] * 64 + lane]);
            acc.x += wgt * xv.x; acc.y += wgt * xv.y;
            acc.z += wgt * xv.z; acc.w += wgt * xv.w;
        }
    }

    #pragma unroll
    for (int o = 32; o; o >>= 1) {
        den0 += __shfl_xor(den0, o);
        den1 += __shfl_xor(den1, o);
    }
    float den = head ? den1 : den0;
    if (deg == 0) den = 1.0f;
    float inv = 1.0f / den;

    float4 xd = unpack_bf16x4(xhb[(size_t)d * 64 + lane]);
    float4 v;
    v.x = acc.x * inv + xd.x;
    v.y = acc.y * inv + xd.y;
    v.z = acc.z * inv + xd.z;
    v.w = acc.w * inv + xd.w;
    float4 o2;
    o2.x = __shfl_xor(v.x, 32);
    o2.y = __shfl_xor(v.y, 32);
    o2.z = __shfl_xor(v.z, 32);
    o2.w = __shfl_xor(v.w, 32);
    if (lane < 32) {
        float4 r;
        r.x = fmaxf(0.5f * (v.x + o2.x), 0.f);
        r.y = fmaxf(0.5f * (v.y + o2.y), 0.f);
        r.z = fmaxf(0.5f * (v.z + o2.z), 0.f);
        r.w = fmaxf(0.5f * (v.w + o2.w), 0.f);
        if (hshuf) {
            int g = d >> 4, m = d & 15;
            int ks = lane >> 3, q = (lane >> 1) & 3;
            int cell = ((g * 4 + ks) * 4 + q) * 16 + m;
            hshuf[cell * 2 + (lane & 1)] = pack_bf16x4(r.x, r.y, r.z, r.w);
        }
        if (pdots) {
            float4 wv = ((const float4*)fw)[lane];
            float pd = r.x * wv.x + r.y * wv.y + r.z * wv.z + r.w * wv.w;
            #pragma unroll
            for (int o = 16; o; o >>= 1) pd += __shfl_xor(pd, o);
            if (lane == 0) pdots[d] = pd;
        }
    }
}

// ---------------------------------------------------------------------------
// Final pooling: segment-sum of per-node dots (batch is sorted)
// ---------------------------------------------------------------------------

__global__ __launch_bounds__(256) void segpool_kernel(const float* __restrict__ p,
                                                      const int* __restrict__ batch,
                                                      float* __restrict__ y, int N, int G) {
    __shared__ float bins[128];
    int t = threadIdx.x;
    if (t < G) bins[t] = 0.f;
    __syncthreads();
    int per = (N + gridDim.x - 1) / gridDim.x;
    int lo = blockIdx.x * per;
    int hi = min(lo + per, N);
    float acc = 0.f;
    int key = -1;
    for (int i = lo + t; i < hi; i += 256) {
        int k = batch[i];
        float v = p[i];
        if (k != key) {
            if (key >= 0) atomicAdd(&bins[key], acc);
            key = k;
            acc = 0.f;
        }
        acc += v;
    }
    if (key >= 0) atomicAdd(&bins[key], acc);
    __syncthreads();
    if (t < G && bins[t] != 0.f) atomicAdd(&y[t], bins[t]);
}

// ---------------------------------------------------------------------------
// Host side
// ---------------------------------------------------------------------------

extern "C" void kernel_launch(void* const* d_in, const int* in_sizes, int n_in,
                              void* d_out, int out_size, void* d_ws, size_t ws_size,
                              hipStream_t stream) {
    const float* x     = (const float*)d_in[0];
    const int*   ei    = (const int*)d_in[1];
    const float* eattr = (const float*)d_in[2];
    const int*   batch = (const int*)d_in[3];
    const float* fw    = (const float*)d_in[16];
    const float* fb    = (const float*)d_in[17];
    float* y = (float*)d_out;

    const int N = in_sizes[0] / DD;     // 50000  (divisible by 16)
    const int E = in_sizes[1] / 2;      // 800000
    const int G = out_size;             // 128

    const int* src = ei;
    const int* dst = ei + E;

    char* ws = (char*)d_ws;
    size_t off = 0;
    auto carve = [&](size_t bytes) {
        char* p = ws + off;
        off += (bytes + 255) & ~(size_t)255;
        return p;
    };
    uint2*  xhb     = (uint2*)carve((size_t)N * 256 * 2);   // bf16 features [N][256]
    uint2*  S0      = (uint2*)carve((size_t)N * 128 * 2);   // shuffled bf16 A (ping)
    uint2*  S1      = (uint2*)carve((size_t)N * 128 * 2);   // shuffled bf16 A (pong)
    unsigned short* Bs = (unsigned short*)carve((size_t)3 * 128 * 256 * 2);
    float2* ae0     = (float2*)carve((size_t)E * 2 * 4);
    float2* ae1     = (float2*)carve((size_t)E * 2 * 4);
    float2* ae2     = (float2*)carve((size_t)E * 2 * 4);
    float*  aiaj    = (float*)carve((size_t)N * 4 * 4);
    int*    row_off = (int*)carve((size_t)(N + 1) * 4);
    int*    cursor  = (int*)carve((size_t)N * 4);
    int*    cnt     = (int*)carve((size_t)N * 4);
    int*    csr_src = (int*)carve((size_t)E * 4);
    int*    csr_eid = (int*)carve((size_t)E * 4);
    float*  pdots   = (float*)carve((size_t)N * 4);
    int*    bsum    = (int*)carve((size_t)256 * 4);

    const int Ngroups = N / 16;         // 3125

    // ---- CSR build + y init: one cooperative kernel ----
    {
        int E_ = E, N_ = N;
        void* args[] = {(void*)&src, (void*)&dst, (void*)&cnt, (void*)&row_off,
                        (void*)&cursor, (void*)&csr_src, (void*)&csr_eid,
                        (void*)&bsum, (void*)&y, (void*)&fb, (void*)&E_, (void*)&N_};
        hipLaunchCooperativeKernel((const void*)csr_coop, dim3(256), dim3(256),
                                   args, 0, stream);
    }

    // ---- all-layer edge transform (CSR-ordered) ----
    int eb = (E + 255) / 256;
    edge_all<<<eb, 256, 0, stream>>>(eattr,
                                     (const float*)d_in[5], (const float*)d_in[6],
                                     (const float*)d_in[9], (const float*)d_in[10],
                                     (const float*)d_in[13], (const float*)d_in[14],
                                     csr_eid, ae0, ae1, ae2, E);

    // ---- operand packs ----
    pack_a0<<<(N * 32 + 255) / 256, 256, 0, stream>>>(x, S0, N);
    pack_w3<<<(3 * 128 * 64 + 255) / 256, 256, 0, stream>>>(
        (const float*)d_in[4], (const float*)d_in[8], (const float*)d_in[12], Bs);

    // ---- 3 GAT layers ----
    int gemm_blocks = (Ngroups * 2 + 3) / 4;
    float2* aes[3] = {ae0, ae1, ae2};
    uint2* Ain[3]  = {S0, S1, S0};
    uint2* Aout[3] = {S1, S0, nullptr};

    for (int l = 0; l < 3; ++l) {
        const float* att  = (const float*)d_in[6 + 4 * l];
        const float* bias = (const float*)d_in[7 + 4 * l];
        const short8* Bl  = (const short8*)(Bs + (size_t)l * 128 * 256);

        gemm_mfma<<<gemm_blocks, 256, 0, stream>>>((const short8*)Ain[l], Bl,
                                                   bias, att, xhb, aiaj, Ngroups);
        aggregate<<<N, 64, 0, stream>>>(xhb, aiaj, aes[l], row_off, csr_src,
                                        Aout[l], fw, (l == 2) ? pdots : nullptr, N);
    }

    // ---- pooling ----
    segpool_kernel<<<128, 256, 0, stream>>>(pdots, batch, y, N, G);
}

// Round 8
// 477.285 us; speedup vs baseline: 1.3716x; 1.3716x over previous
//
#include <hip/hip_runtime.h>
#include <hip/hip_bf16.h>

// Problem constants (match reference)
#define DD 128      // feature dim
#define AA 4        // edge attr dim
#define HH 2        // heads

typedef short short8 __attribute__((ext_vector_type(8)));
typedef float f32x4 __attribute__((ext_vector_type(4)));

// bf16 pack/unpack (RNE)
__device__ inline unsigned short f2bf(float f) {
    unsigned u = __float_as_uint(f);
    unsigned r = (u + 0x7fffu + ((u >> 16) & 1u)) >> 16;
    return (unsigned short)r;
}
__device__ inline float4 unpack_bf16x4(uint2 v) {
    float4 r;
    r.x = __uint_as_float(v.x << 16);
    r.y = __uint_as_float(v.x & 0xffff0000u);
    r.z = __uint_as_float(v.y << 16);
    r.w = __uint_as_float(v.y & 0xffff0000u);
    return r;
}
__device__ inline uint2 pack_bf16x4(float a, float b, float c, float d) {
    uint2 p;
    p.x = (unsigned)f2bf(a) | ((unsigned)f2bf(b) << 16);
    p.y = (unsigned)f2bf(c) | ((unsigned)f2bf(d) << 16);
    return p;
}

// ---------------------------------------------------------------------------
// CSR build: full-width histogram -> 3-kernel scan -> scatter (round-6 style;
// cooperative single-kernel version was 4x slower: 256-block cap = 11% occ).
// ---------------------------------------------------------------------------

__global__ void hist_kernel(const int* __restrict__ dst, int* __restrict__ cnt, int E) {
    int e = blockIdx.x * blockDim.x + threadIdx.x;
    if (e < E) atomicAdd(&cnt[dst[e]], 1);
}

// scan1: per-1024-chunk sums; block 0 also inits y = fb
__global__ __launch_bounds__(256) void scan1(const int* __restrict__ cnt,
                                             int* __restrict__ bsum, int N,
                                             float* __restrict__ y,
                                             const float* __restrict__ fb) {
    __shared__ int wsh[4];
    int b = blockIdx.x, t = threadIdx.x;
    int lane = t & 63, w = t >> 6;
    if (b == 0 && t < 128) y[t] = fb[0];
    int base = b * 1024;
    int v = 0;
    #pragma unroll
    for (int i = 0; i < 4; ++i) {
        int idx = base + i * 256 + t;
        v += (idx < N) ? cnt[idx] : 0;
    }
    #pragma unroll
    for (int o = 32; o; o >>= 1) v += __shfl_xor(v, o);
    if (lane == 0) wsh[w] = v;
    __syncthreads();
    if (t == 0) bsum[b] = wsh[0] + wsh[1] + wsh[2] + wsh[3];
}

__global__ __launch_bounds__(64) void scan2(int* __restrict__ bsum, int NB,
                                            int* __restrict__ total) {
    int t = threadIdx.x;
    int v = (t < NB) ? bsum[t] : 0;
    int x = v;
    #pragma unroll
    for (int o = 1; o < 64; o <<= 1) {
        int u = __shfl_up(x, o);
        if (t >= o) x += u;
    }
    if (t < NB) bsum[t] = x - v;
    if (t == 63) *total = x;
}

__global__ __launch_bounds__(256) void scan3(const int* __restrict__ cnt,
                                             const int* __restrict__ bsum,
                                             int* __restrict__ row_off,
                                             int* __restrict__ cursor, int N) {
    __shared__ int wtot[4];
    __shared__ int carry;
    int b = blockIdx.x, t = threadIdx.x;
    int lane = t & 63, w = t >> 6;
    if (t == 0) carry = bsum[b];
    __syncthreads();
    int base = b * 1024;
    #pragma unroll
    for (int it = 0; it < 4; ++it) {
        int idx = base + it * 256 + t;
        int v = (idx < N) ? cnt[idx] : 0;
        int x = v;
        #pragma unroll
        for (int o = 1; o < 64; o <<= 1) {
            int u = __shfl_up(x, o);
            if (lane >= o) x += u;
        }
        if (lane == 63) wtot[w] = x;
        __syncthreads();
        int woff = 0;
        for (int i = 0; i < w; ++i) woff += wtot[i];
        int c = carry;
        __syncthreads();
        if (t == 255) carry = c + woff + x;
        int ex = c + woff + x - v;
        if (idx < N) { row_off[idx] = ex; cursor[idx] = ex; }
        __syncthreads();
    }
}

__global__ void scatter_kernel(const int* __restrict__ src, const int* __restrict__ dst,
                               int* __restrict__ cursor, int* __restrict__ csr_src,
                               int* __restrict__ csr_eid, int E) {
    int e = blockIdx.x * blockDim.x + threadIdx.x;
    if (e >= E) return;
    int p = atomicAdd(&cursor[dst[e]], 1);
    csr_src[p] = src[e];
    csr_eid[p] = e;
}

// ---------------------------------------------------------------------------
// Fragment-shuffled operand packing for MFMA GEMM.
// A_shuf (bf16): cell(g,ks,q,m) = short8 of A[row=g*16+m][k=ks*32+q*8 .. +8]
//   flat short8 idx = ((g*4+ks)*4+q)*16 + m
// B_shuf (bf16): cell(ct,ks,q,n) = short8 of W[k=ks*32+q*8 .. +8][col=ct*16+n]
//   flat short8 idx = ((ct*4+ks)*4+q)*16 + n
// ---------------------------------------------------------------------------

__global__ __launch_bounds__(256) void pack_a0(const float* __restrict__ X,
                                               uint2* __restrict__ As, int N) {
    int t = blockIdx.x * blockDim.x + threadIdx.x;
    if (t >= N * 32) return;
    int r = t >> 5, kq4 = t & 31;
    float4 v = ((const float4*)X)[t];
    int g = r >> 4, m = r & 15;
    int ks = kq4 >> 3, q = (kq4 >> 1) & 3;
    int cell = ((g * 4 + ks) * 4 + q) * 16 + m;
    As[cell * 2 + (kq4 & 1)] = pack_bf16x4(v.x, v.y, v.z, v.w);
}

__global__ __launch_bounds__(256) void pack_w3(const float* __restrict__ W0,
                                               const float* __restrict__ W1,
                                               const float* __restrict__ W2,
                                               unsigned short* __restrict__ Bs) {
    int t = blockIdx.x * blockDim.x + threadIdx.x;
    if (t >= 3 * 128 * 64) return;
    int l = t / (128 * 64);
    int r = t - l * (128 * 64);
    const float* W = (l == 0) ? W0 : (l == 1) ? W1 : W2;
    unsigned short* B = Bs + (size_t)l * 128 * 256;
    int k = r >> 6, c4g = r & 63;
    float4 v = ((const float4*)W)[r];
    int ct = c4g >> 2, n0 = (c4g & 3) * 4;
    int ks = k >> 5, q = (k >> 3) & 3, j = k & 7;
    int cellbase = ((ct * 4 + ks) * 4 + q) * 16 + n0;
    B[(cellbase + 0) * 8 + j] = f2bf(v.x);
    B[(cellbase + 1) * 8 + j] = f2bf(v.y);
    B[(cellbase + 2) * 8 + j] = f2bf(v.z);
    B[(cellbase + 3) * 8 + j] = f2bf(v.w);
}

// ---------------------------------------------------------------------------
// MFMA GEMM + fused epilogue. One wave per (16-row group, head-half):
// 8 col-tiles of 16; K=128 in 4 steps of 32. Emits bf16 xhb (LDS transpose,
// wave-private -> no barrier) and this half's attention logits.
// ---------------------------------------------------------------------------

__global__ __launch_bounds__(256) void gemm_mfma(const short8* __restrict__ As,
                                                 const short8* __restrict__ Bs,
                                                 const float* __restrict__ bias,
                                                 const float* __restrict__ att,
                                                 uint2* __restrict__ xhb,
                                                 float* __restrict__ aiaj, int Ngroups) {
    __shared__ __align__(16) unsigned short sh[4][16 * 132];
    int w = threadIdx.x >> 6;
    int flat = blockIdx.x * 4 + w;
    int wid = flat >> 1, half = flat & 1;
    int lane = threadIdx.x & 63;
    if (wid >= Ngroups) return;
    int q = lane >> 4, m = lane & 15;

    const short8* Ag = As + (size_t)wid * 256;
    f32x4 acc[8];
    #pragma unroll
    for (int c8 = 0; c8 < 8; ++c8) acc[c8] = (f32x4){0.f, 0.f, 0.f, 0.f};

    #pragma unroll
    for (int ks = 0; ks < 4; ++ks) {
        short8 a = Ag[ks * 64 + lane];
        #pragma unroll
        for (int c8 = 0; c8 < 8; ++c8) {
            short8 b = Bs[(half * 8 + c8) * 256 + ks * 64 + lane];
            acc[c8] = __builtin_amdgcn_mfma_f32_16x16x32_bf16(a, b, acc[c8], 0, 0, 0);
        }
    }

    // Epilogue. C/D layout: col(local) = c8*16+m, row(local) = q*4+reg.
    const float* atth = att + half * (2 * DD + AA);
    float ai[4] = {}, aj[4] = {};
    #pragma unroll
    for (int c8 = 0; c8 < 8; ++c8) {
        int col = c8 * 16 + m;
        float aS = atth[col];
        float aD = atth[DD + col];
        float bv = bias[(half * 8 + c8) * 16 + m];
        #pragma unroll
        for (int reg = 0; reg < 4; ++reg) {
            float val = acc[c8][reg] + bv;
            sh[w][(q * 4 + reg) * 132 + col] = f2bf(val);
            ai[reg] += val * aS;
            aj[reg] += val * aD;
        }
    }
    #pragma unroll
    for (int o = 1; o < 16; o <<= 1) {
        #pragma unroll
        for (int reg = 0; reg < 4; ++reg) {
            ai[reg] += __shfl_xor(ai[reg], o);
            aj[reg] += __shfl_xor(aj[reg], o);
        }
    }
    if (m == 0) {
        #pragma unroll
        for (int reg = 0; reg < 4; ++reg) {
            int row = wid * 16 + q * 4 + reg;
            aiaj[row * 4 + half] = ai[reg];
            aiaj[row * 4 + 2 + half] = aj[reg];
        }
    }
    // wave-private LDS tile -> coalesced bf16 store (2 rows per inst)
    #pragma unroll
    for (int r2 = 0; r2 < 8; ++r2) {
        int row = r2 * 2 + (lane >> 5);
        uint2 v = *(const uint2*)&sh[w][row * 132 + (lane & 31) * 4];
        xhb[(size_t)(wid * 16 + row) * 64 + half * 32 + (lane & 31)] = v;
    }
}

// ---------------------------------------------------------------------------
// Fused edge transform for ALL 3 layers, CSR-ordered (coalesced writes,
// one random 16B read per edge).
// ---------------------------------------------------------------------------

__device__ inline void edge_stage(const float4& ev, const float* __restrict__ linE,
                                  const float* __restrict__ att, float2& ae, float4& enext) {
    float eh[8];
    #pragma unroll
    for (int c = 0; c < 8; ++c)
        eh[c] = ev.x * linE[c] + ev.y * linE[8 + c] + ev.z * linE[16 + c] + ev.w * linE[24 + c];
    float a0 = 0.f, a1 = 0.f;
    #pragma unroll
    for (int a = 0; a < 4; ++a) {
        a0 += eh[a]     * att[2 * DD + a];
        a1 += eh[4 + a] * att[(2 * DD + AA) + 2 * DD + a];
    }
    ae.x = a0; ae.y = a1;
    enext.x = fmaxf(0.5f * (eh[0] + eh[4]), 0.f);
    enext.y = fmaxf(0.5f * (eh[1] + eh[5]), 0.f);
    enext.z = fmaxf(0.5f * (eh[2] + eh[6]), 0.f);
    enext.w = fmaxf(0.5f * (eh[3] + eh[7]), 0.f);
}

__global__ __launch_bounds__(256) void edge_all(const float* __restrict__ ein,
                                                const float* __restrict__ linE0, const float* __restrict__ att0,
                                                const float* __restrict__ linE1, const float* __restrict__ att1,
                                                const float* __restrict__ linE2, const float* __restrict__ att2,
                                                const int* __restrict__ csr_eid,
                                                float2* __restrict__ ae0,
                                                float2* __restrict__ ae1,
                                                float2* __restrict__ ae2, int E) {
    int p = blockIdx.x * blockDim.x + threadIdx.x;
    if (p >= E) return;
    int eid = csr_eid[p];
    float4 ev = ((const float4*)ein)[eid];
    float2 ae; float4 en;
    edge_stage(ev, linE0, att0, ae, en); ae0[p] = ae;
    edge_stage(en, linE1, att1, ae, ev); ae1[p] = ae;
    edge_stage(ev, linE2, att2, ae, en); ae2[p] = ae;
}

// ---------------------------------------------------------------------------
// Aggregation: one wave per dst node, BARRIER-FREE (single-wave block; LDS
// RAW within a wave is ordered by lgkmcnt). Single-pass softmax (shift-
// invariant, logits O(10)). bf16 gather payload; bf16 skip.
// ---------------------------------------------------------------------------

__global__ __launch_bounds__(64) void aggregate(const uint2* __restrict__ xhb,
                                                const float* __restrict__ aiaj,
                                                const float2* __restrict__ ae,
                                                const int* __restrict__ row_off,
                                                const int* __restrict__ csr_src,
                                                uint2* __restrict__ hshuf,
                                                const float* __restrict__ fw,
                                                float* __restrict__ pdots, int N) {
    int d = blockIdx.x;
    int lane = threadIdx.x;
    int s0 = row_off[d], s1 = row_off[d + 1];
    int deg = s1 - s0;
    const float2* aiaj2 = (const float2*)aiaj;
    float2 ajv = aiaj2[d * 2 + 1];   // (aj0, aj1)

    __shared__ float lex[64][2];
    __shared__ int lsrc[64];
    float4 acc = {0.f, 0.f, 0.f, 0.f};
    float den0 = 0.f, den1 = 0.f;
    int head = lane >> 5;

    for (int c = 0; c < deg; c += 64) {
        int n = min(64, deg - c);
        if (lane < n) {
            int p = s0 + c + lane;
            int s = csr_src[p];
            float2 aiv = aiaj2[s * 2];
            float2 aev = ae[p];
            float a0 = aiv.x + ajv.x + aev.x; a0 = a0 > 0.f ? a0 : 0.2f * a0;
            float a1 = aiv.y + ajv.y + aev.y; a1 = a1 > 0.f ? a1 : 0.2f * a1;
            float e0 = __expf(a0), e1 = __expf(a1);
            den0 += e0; den1 += e1;
            lex[lane][0] = e0; lex[lane][1] = e1;
            lsrc[lane] = s;
        }
        #pragma unroll 4
        for (int j = 0; j < n; ++j) {
            float wgt = lex[j][head];
            float4 xv = unpack_bf16x4(xhb[(size_t)lsrc[j] * 64 + lane]);
            acc.x += wgt * xv.x; acc.y += wgt * xv.y;
            acc.z += wgt * xv.z; acc.w += wgt * xv.w;
        }
    }

    #pragma unroll
    for (int o = 32; o; o >>= 1) {
        den0 += __shfl_xor(den0, o);
        den1 += __shfl_xor(den1, o);
    }
    float den = head ? den1 : den0;
    if (deg == 0) den = 1.0f;
    float inv = 1.0f / den;

    float4 xd = unpack_bf16x4(xhb[(size_t)d * 64 + lane]);
    float4 v;
    v.x = acc.x * inv + xd.x;
    v.y = acc.y * inv + xd.y;
    v.z = acc.z * inv + xd.z;
    v.w = acc.w * inv + xd.w;
    float4 o2;
    o2.x = __shfl_xor(v.x, 32);
    o2.y = __shfl_xor(v.y, 32);
    o2.z = __shfl_xor(v.z, 32);
    o2.w = __shfl_xor(v.w, 32);
    if (lane < 32) {
        float4 r;
        r.x = fmaxf(0.5f * (v.x + o2.x), 0.f);
        r.y = fmaxf(0.5f * (v.y + o2.y), 0.f);
        r.z = fmaxf(0.5f * (v.z + o2.z), 0.f);
        r.w = fmaxf(0.5f * (v.w + o2.w), 0.f);
        if (hshuf) {
            int g = d >> 4, m = d & 15;
            int ks = lane >> 3, q = (lane >> 1) & 3;
            int cell = ((g * 4 + ks) * 4 + q) * 16 + m;
            hshuf[cell * 2 + (lane & 1)] = pack_bf16x4(r.x, r.y, r.z, r.w);
        }
        if (pdots) {
            float4 wv = ((const float4*)fw)[lane];
            float pd = r.x * wv.x + r.y * wv.y + r.z * wv.z + r.w * wv.w;
            #pragma unroll
            for (int o = 16; o; o >>= 1) pd += __shfl_xor(pd, o);
            if (lane == 0) pdots[d] = pd;
        }
    }
}

// ---------------------------------------------------------------------------
// Final pooling: segment-sum of per-node dots (batch is sorted)
// ---------------------------------------------------------------------------

__global__ __launch_bounds__(256) void segpool_kernel(const float* __restrict__ p,
                                                      const int* __restrict__ batch,
                                                      float* __restrict__ y, int N, int G) {
    __shared__ float bins[128];
    int t = threadIdx.x;
    if (t < G) bins[t] = 0.f;
    __syncthreads();
    int per = (N + gridDim.x - 1) / gridDim.x;
    int lo = blockIdx.x * per;
    int hi = min(lo + per, N);
    float acc = 0.f;
    int key = -1;
    for (int i = lo + t; i < hi; i += 256) {
        int k = batch[i];
        float v = p[i];
        if (k != key) {
            if (key >= 0) atomicAdd(&bins[key], acc);
            key = k;
            acc = 0.f;
        }
        acc += v;
    }
    if (key >= 0) atomicAdd(&bins[key], acc);
    __syncthreads();
    if (t < G && bins[t] != 0.f) atomicAdd(&y[t], bins[t]);
}

// ---------------------------------------------------------------------------
// Host side
// ---------------------------------------------------------------------------

extern "C" void kernel_launch(void* const* d_in, const int* in_sizes, int n_in,
                              void* d_out, int out_size, void* d_ws, size_t ws_size,
                              hipStream_t stream) {
    const float* x     = (const float*)d_in[0];
    const int*   ei    = (const int*)d_in[1];
    const float* eattr = (const float*)d_in[2];
    const int*   batch = (const int*)d_in[3];
    const float* fw    = (const float*)d_in[16];
    const float* fb    = (const float*)d_in[17];
    float* y = (float*)d_out;

    const int N = in_sizes[0] / DD;     // 50000  (divisible by 16)
    const int E = in_sizes[1] / 2;      // 800000
    const int G = out_size;             // 128

    const int* src = ei;
    const int* dst = ei + E;

    char* ws = (char*)d_ws;
    size_t off = 0;
    auto carve = [&](size_t bytes) {
        char* p = ws + off;
        off += (bytes + 255) & ~(size_t)255;
        return p;
    };
    uint2*  xhb     = (uint2*)carve((size_t)N * 256 * 2);   // bf16 features [N][256]
    uint2*  S0      = (uint2*)carve((size_t)N * 128 * 2);   // shuffled bf16 A (ping)
    uint2*  S1      = (uint2*)carve((size_t)N * 128 * 2);   // shuffled bf16 A (pong)
    unsigned short* Bs = (unsigned short*)carve((size_t)3 * 128 * 256 * 2);
    float2* ae0     = (float2*)carve((size_t)E * 2 * 4);
    float2* ae1     = (float2*)carve((size_t)E * 2 * 4);
    float2* ae2     = (float2*)carve((size_t)E * 2 * 4);
    float*  aiaj    = (float*)carve((size_t)N * 4 * 4);
    int*    row_off = (int*)carve((size_t)(N + 1) * 4);
    int*    cursor  = (int*)carve((size_t)N * 4);
    int*    cnt     = (int*)carve((size_t)N * 4);
    int*    csr_src = (int*)carve((size_t)E * 4);
    int*    csr_eid = (int*)carve((size_t)E * 4);
    float*  pdots   = (float*)carve((size_t)N * 4);
    int*    bsum    = (int*)carve((size_t)256 * 4);

    const int NB = (N + 1023) / 1024;   // 49 <= 64
    const int Ngroups = N / 16;         // 3125

    // ---- CSR build (full-width kernels) + y init ----
    hipMemsetAsync(cnt, 0, (size_t)N * 4, stream);
    int eb = (E + 255) / 256;
    hist_kernel<<<eb, 256, 0, stream>>>(dst, cnt, E);
    scan1<<<NB, 256, 0, stream>>>(cnt, bsum, N, y, fb);
    scan2<<<1, 64, 0, stream>>>(bsum, NB, row_off + N);
    scan3<<<NB, 256, 0, stream>>>(cnt, bsum, row_off, cursor, N);
    scatter_kernel<<<eb, 256, 0, stream>>>(src, dst, cursor, csr_src, csr_eid, E);

    // ---- all-layer edge transform (CSR-ordered) ----
    edge_all<<<eb, 256, 0, stream>>>(eattr,
                                     (const float*)d_in[5], (const float*)d_in[6],
                                     (const float*)d_in[9], (const float*)d_in[10],
                                     (const float*)d_in[13], (const float*)d_in[14],
                                     csr_eid, ae0, ae1, ae2, E);

    // ---- operand packs ----
    pack_a0<<<(N * 32 + 255) / 256, 256, 0, stream>>>(x, S0, N);
    pack_w3<<<(3 * 128 * 64 + 255) / 256, 256, 0, stream>>>(
        (const float*)d_in[4], (const float*)d_in[8], (const float*)d_in[12], Bs);

    // ---- 3 GAT layers ----
    int gemm_blocks = (Ngroups * 2 + 3) / 4;
    float2* aes[3] = {ae0, ae1, ae2};
    uint2* Ain[3]  = {S0, S1, S0};
    uint2* Aout[3] = {S1, S0, nullptr};

    for (int l = 0; l < 3; ++l) {
        const float* att  = (const float*)d_in[6 + 4 * l];
        const float* bias = (const float*)d_in[7 + 4 * l];
        const short8* Bl  = (const short8*)(Bs + (size_t)l * 128 * 256);

        gemm_mfma<<<gemm_blocks, 256, 0, stream>>>((const short8*)Ain[l], Bl,
                                                   bias, att, xhb, aiaj, Ngroups);
        aggregate<<<N, 64, 0, stream>>>(xhb, aiaj, aes[l], row_off, csr_src,
                                        Aout[l], fw, (l == 2) ? pdots : nullptr, N);
    }

    // ---- pooling ----
    segpool_kernel<<<128, 256, 0, stream>>>(pdots, batch, y, N, G);
}

// Round 9
// 451.051 us; speedup vs baseline: 1.4514x; 1.0582x over previous
//
#include <hip/hip_runtime.h>
#include <hip/hip_bf16.h>

// Problem constants (match reference)
#define DD 128      // feature dim
#define AA 4        // edge attr dim
#define HH 2        // heads

typedef short short8 __attribute__((ext_vector_type(8)));
typedef float f32x4 __attribute__((ext_vector_type(4)));

// bf16 pack/unpack (RNE)
__device__ inline unsigned short f2bf(float f) {
    unsigned u = __float_as_uint(f);
    unsigned r = (u + 0x7fffu + ((u >> 16) & 1u)) >> 16;
    return (unsigned short)r;
}
__device__ inline float4 unpack_bf16x4(uint2 v) {
    float4 r;
    r.x = __uint_as_float(v.x << 16);
    r.y = __uint_as_float(v.x & 0xffff0000u);
    r.z = __uint_as_float(v.y << 16);
    r.w = __uint_as_float(v.y & 0xffff0000u);
    return r;
}
__device__ inline uint2 pack_bf16x4(float a, float b, float c, float d) {
    uint2 p;
    p.x = (unsigned)f2bf(a) | ((unsigned)f2bf(b) << 16);
    p.y = (unsigned)f2bf(c) | ((unsigned)f2bf(d) << 16);
    return p;
}

// ---------------------------------------------------------------------------
// CSR build, pass 1: histogram + per-edge rank in ONE atomic pass.
// ---------------------------------------------------------------------------

__global__ void rank_kernel(const int* __restrict__ dst, int* __restrict__ cnt,
                            int* __restrict__ rank, int E) {
    int e = blockIdx.x * blockDim.x + threadIdx.x;
    if (e < E) rank[e] = atomicAdd(&cnt[dst[e]], 1);
}

// scan1: per-1024-chunk sums; block 0 also inits y = fb
__global__ __launch_bounds__(256) void scan1(const int* __restrict__ cnt,
                                             int* __restrict__ bsum, int N,
                                             float* __restrict__ y,
                                             const float* __restrict__ fb) {
    __shared__ int wsh[4];
    int b = blockIdx.x, t = threadIdx.x;
    int lane = t & 63, w = t >> 6;
    if (b == 0 && t < 128) y[t] = fb[0];
    int base = b * 1024;
    int v = 0;
    #pragma unroll
    for (int i = 0; i < 4; ++i) {
        int idx = base + i * 256 + t;
        v += (idx < N) ? cnt[idx] : 0;
    }
    #pragma unroll
    for (int o = 32; o; o >>= 1) v += __shfl_xor(v, o);
    if (lane == 0) wsh[w] = v;
    __syncthreads();
    if (t == 0) bsum[b] = wsh[0] + wsh[1] + wsh[2] + wsh[3];
}

__global__ __launch_bounds__(64) void scan2(int* __restrict__ bsum, int NB,
                                            int* __restrict__ total) {
    int t = threadIdx.x;
    int v = (t < NB) ? bsum[t] : 0;
    int x = v;
    #pragma unroll
    for (int o = 1; o < 64; o <<= 1) {
        int u = __shfl_up(x, o);
        if (t >= o) x += u;
    }
    if (t < NB) bsum[t] = x - v;
    if (t == 63) *total = x;
}

__global__ __launch_bounds__(256) void scan3(const int* __restrict__ cnt,
                                             const int* __restrict__ bsum,
                                             int* __restrict__ row_off, int N) {
    __shared__ int wtot[4];
    __shared__ int carry;
    int b = blockIdx.x, t = threadIdx.x;
    int lane = t & 63, w = t >> 6;
    if (t == 0) carry = bsum[b];
    __syncthreads();
    int base = b * 1024;
    #pragma unroll
    for (int it = 0; it < 4; ++it) {
        int idx = base + it * 256 + t;
        int v = (idx < N) ? cnt[idx] : 0;
        int x = v;
        #pragma unroll
        for (int o = 1; o < 64; o <<= 1) {
            int u = __shfl_up(x, o);
            if (lane >= o) x += u;
        }
        if (lane == 63) wtot[w] = x;
        __syncthreads();
        int woff = 0;
        for (int i = 0; i < w; ++i) woff += wtot[i];
        int c = carry;
        __syncthreads();
        if (t == 255) carry = c + woff + x;
        int ex = c + woff + x - v;
        if (idx < N) row_off[idx] = ex;
        __syncthreads();
    }
}

// CSR build, pass 2: p = row_off[dst] + rank  (no atomics, 1 random 4B write)
__global__ void perm_kernel(const int* __restrict__ dst, const int* __restrict__ rank,
                            const int* __restrict__ row_off, int* __restrict__ perm, int E) {
    int e = blockIdx.x * blockDim.x + threadIdx.x;
    if (e >= E) return;
    perm[row_off[dst[e]] + rank[e]] = e;
}

// ---------------------------------------------------------------------------
// Fused edge transform (all 3 layers, CSR-ordered, write-coalesced) +
// pack_a0 + pack_w3 in one kernel via blockIdx range split.
//
// A_shuf (bf16): cell(g,ks,q,m) = short8 of A[row=g*16+m][k=ks*32+q*8 .. +8]
// B_shuf (bf16): cell(ct,ks,q,n) = short8 of W[k=ks*32+q*8 .. +8][col=ct*16+n]
// ---------------------------------------------------------------------------

__device__ inline void edge_stage(const float4& ev, const float* __restrict__ linE,
                                  const float* __restrict__ att, float2& ae, float4& enext) {
    float eh[8];
    #pragma unroll
    for (int c = 0; c < 8; ++c)
        eh[c] = ev.x * linE[c] + ev.y * linE[8 + c] + ev.z * linE[16 + c] + ev.w * linE[24 + c];
    float a0 = 0.f, a1 = 0.f;
    #pragma unroll
    for (int a = 0; a < 4; ++a) {
        a0 += eh[a]     * att[2 * DD + a];
        a1 += eh[4 + a] * att[(2 * DD + AA) + 2 * DD + a];
    }
    ae.x = a0; ae.y = a1;
    enext.x = fmaxf(0.5f * (eh[0] + eh[4]), 0.f);
    enext.y = fmaxf(0.5f * (eh[1] + eh[5]), 0.f);
    enext.z = fmaxf(0.5f * (eh[2] + eh[6]), 0.f);
    enext.w = fmaxf(0.5f * (eh[3] + eh[7]), 0.f);
}

__global__ __launch_bounds__(256) void prep_fused(
        // edge part
        const float* __restrict__ ein, const int* __restrict__ src,
        const int* __restrict__ perm,
        const float* __restrict__ linE0, const float* __restrict__ att0,
        const float* __restrict__ linE1, const float* __restrict__ att1,
        const float* __restrict__ linE2, const float* __restrict__ att2,
        int* __restrict__ csr_src,
        float2* __restrict__ ae0, float2* __restrict__ ae1, float2* __restrict__ ae2,
        int E, int ebE,
        // pack_a0 part
        const float* __restrict__ X, uint2* __restrict__ As, int N, int ebA,
        // pack_w3 part
        const float* __restrict__ W0, const float* __restrict__ W1,
        const float* __restrict__ W2, unsigned short* __restrict__ Bs) {
    int b = blockIdx.x;
    if (b < ebE) {
        int p = b * 256 + threadIdx.x;
        if (p >= E) return;
        int e = perm[p];                       // coalesced
        csr_src[p] = src[e];                   // random read, coalesced write
        float4 ev = ((const float4*)ein)[e];   // random 16B read (L3-resident)
        float2 ae; float4 en;
        edge_stage(ev, linE0, att0, ae, en); ae0[p] = ae;
        edge_stage(en, linE1, att1, ae, ev); ae1[p] = ae;
        edge_stage(ev, linE2, att2, ae, en); ae2[p] = ae;
    } else if (b < ebE + ebA) {
        int t = (b - ebE) * 256 + threadIdx.x;
        if (t >= N * 32) return;
        int r = t >> 5, kq4 = t & 31;
        float4 v = ((const float4*)X)[t];
        int g = r >> 4, m = r & 15;
        int ks = kq4 >> 3, q = (kq4 >> 1) & 3;
        int cell = ((g * 4 + ks) * 4 + q) * 16 + m;
        As[cell * 2 + (kq4 & 1)] = pack_bf16x4(v.x, v.y, v.z, v.w);
    } else {
        int t = (b - ebE - ebA) * 256 + threadIdx.x;
        if (t >= 3 * 128 * 64) return;
        int l = t / (128 * 64);
        int r = t - l * (128 * 64);
        const float* W = (l == 0) ? W0 : (l == 1) ? W1 : W2;
        unsigned short* B = Bs + (size_t)l * 128 * 256;
        int k = r >> 6, c4g = r & 63;
        float4 v = ((const float4*)W)[r];
        int ct = c4g >> 2, n0 = (c4g & 3) * 4;
        int ks = k >> 5, q = (k >> 3) & 3, j = k & 7;
        int cellbase = ((ct * 4 + ks) * 4 + q) * 16 + n0;
        B[(cellbase + 0) * 8 + j] = f2bf(v.x);
        B[(cellbase + 1) * 8 + j] = f2bf(v.y);
        B[(cellbase + 2) * 8 + j] = f2bf(v.z);
        B[(cellbase + 3) * 8 + j] = f2bf(v.w);
    }
}

// ---------------------------------------------------------------------------
// MFMA GEMM + fused epilogue. One wave per (16-row group, head-half):
// 8 col-tiles of 16; K=128 in 4 steps of 32. Emits bf16 xhb (LDS transpose,
// wave-private -> no barrier) and this half's attention logits.
// ---------------------------------------------------------------------------

__global__ __launch_bounds__(256) void gemm_mfma(const short8* __restrict__ As,
                                                 const short8* __restrict__ Bs,
                                                 const float* __restrict__ bias,
                                                 const float* __restrict__ att,
                                                 uint2* __restrict__ xhb,
                                                 float* __restrict__ aiaj, int Ngroups) {
    __shared__ __align__(16) unsigned short sh[4][16 * 132];
    int w = threadIdx.x >> 6;
    int flat = blockIdx.x * 4 + w;
    int wid = flat >> 1, half = flat & 1;
    int lane = threadIdx.x & 63;
    if (wid >= Ngroups) return;
    int q = lane >> 4, m = lane & 15;

    const short8* Ag = As + (size_t)wid * 256;
    f32x4 acc[8];
    #pragma unroll
    for (int c8 = 0; c8 < 8; ++c8) acc[c8] = (f32x4){0.f, 0.f, 0.f, 0.f};

    #pragma unroll
    for (int ks = 0; ks < 4; ++ks) {
        short8 a = Ag[ks * 64 + lane];
        #pragma unroll
        for (int c8 = 0; c8 < 8; ++c8) {
            short8 b = Bs[(half * 8 + c8) * 256 + ks * 64 + lane];
            acc[c8] = __builtin_amdgcn_mfma_f32_16x16x32_bf16(a, b, acc[c8], 0, 0, 0);
        }
    }

    // Epilogue. C/D layout: col(local) = c8*16+m, row(local) = q*4+reg.
    const float* atth = att + half * (2 * DD + AA);
    float ai[4] = {}, aj[4] = {};
    #pragma unroll
    for (int c8 = 0; c8 < 8; ++c8) {
        int col = c8 * 16 + m;
        float aS = atth[col];
        float aD = atth[DD + col];
        float bv = bias[(half * 8 + c8) * 16 + m];
        #pragma unroll
        for (int reg = 0; reg < 4; ++reg) {
            float val = acc[c8][reg] + bv;
            sh[w][(q * 4 + reg) * 132 + col] = f2bf(val);
            ai[reg] += val * aS;
            aj[reg] += val * aD;
        }
    }
    #pragma unroll
    for (int o = 1; o < 16; o <<= 1) {
        #pragma unroll
        for (int reg = 0; reg < 4; ++reg) {
            ai[reg] += __shfl_xor(ai[reg], o);
            aj[reg] += __shfl_xor(aj[reg], o);
        }
    }
    if (m == 0) {
        #pragma unroll
        for (int reg = 0; reg < 4; ++reg) {
            int row = wid * 16 + q * 4 + reg;
            aiaj[row * 4 + half] = ai[reg];
            aiaj[row * 4 + 2 + half] = aj[reg];
        }
    }
    // wave-private LDS tile -> coalesced bf16 store (2 rows per inst)
    #pragma unroll
    for (int r2 = 0; r2 < 8; ++r2) {
        int row = r2 * 2 + (lane >> 5);
        uint2 v = *(const uint2*)&sh[w][row * 132 + (lane & 31) * 4];
        xhb[(size_t)(wid * 16 + row) * 64 + half * 32 + (lane & 31)] = v;
    }
}

// ---------------------------------------------------------------------------
// Aggregation: one wave per dst node, barrier-free. Single-pass softmax
// (shift-invariant, logits O(10)). bf16 gather payload; bf16 skip.
// ---------------------------------------------------------------------------

__global__ __launch_bounds__(64) void aggregate(const uint2* __restrict__ xhb,
                                                const float* __restrict__ aiaj,
                                                const float2* __restrict__ ae,
                                                const int* __restrict__ row_off,
                                                const int* __restrict__ csr_src,
                                                uint2* __restrict__ hshuf,
                                                const float* __restrict__ fw,
                                                float* __restrict__ pdots, int N) {
    int d = blockIdx.x;
    int lane = threadIdx.x;
    int s0 = row_off[d], s1 = row_off[d + 1];
    int deg = s1 - s0;
    const float2* aiaj2 = (const float2*)aiaj;
    float2 ajv = aiaj2[d * 2 + 1];   // (aj0, aj1)

    __shared__ float lex[64][2];
    __shared__ int lsrc[64];
    float4 acc = {0.f, 0.f, 0.f, 0.f};
    float den0 = 0.f, den1 = 0.f;
    int head = lane >> 5;

    for (int c = 0; c < deg; c += 64) {
        int n = min(64, deg - c);
        if (lane < n) {
            int p = s0 + c + lane;
            int s = csr_src[p];
            float2 aiv = aiaj2[s * 2];
            float2 aev = ae[p];
            float a0 = aiv.x + ajv.x + aev.x; a0 = a0 > 0.f ? a0 : 0.2f * a0;
            float a1 = aiv.y + ajv.y + aev.y; a1 = a1 > 0.f ? a1 : 0.2f * a1;
            float e0 = __expf(a0), e1 = __expf(a1);
            den0 += e0; den1 += e1;
            lex[lane][0] = e0; lex[lane][1] = e1;
            lsrc[lane] = s;
        }
        #pragma unroll 4
        for (int j = 0; j < n; ++j) {
            float wgt = lex[j][head];
            float4 xv = unpack_bf16x4(xhb[(size_t)lsrc[j] * 64 + lane]);
            acc.x += wgt * xv.x; acc.y += wgt * xv.y;
            acc.z += wgt * xv.z; acc.w += wgt * xv.w;
        }
    }

    #pragma unroll
    for (int o = 32; o; o >>= 1) {
        den0 += __shfl_xor(den0, o);
        den1 += __shfl_xor(den1, o);
    }
    float den = head ? den1 : den0;
    if (deg == 0) den = 1.0f;
    float inv = 1.0f / den;

    float4 xd = unpack_bf16x4(xhb[(size_t)d * 64 + lane]);
    float4 v;
    v.x = acc.x * inv + xd.x;
    v.y = acc.y * inv + xd.y;
    v.z = acc.z * inv + xd.z;
    v.w = acc.w * inv + xd.w;
    float4 o2;
    o2.x = __shfl_xor(v.x, 32);
    o2.y = __shfl_xor(v.y, 32);
    o2.z = __shfl_xor(v.z, 32);
    o2.w = __shfl_xor(v.w, 32);
    if (lane < 32) {
        float4 r;
        r.x = fmaxf(0.5f * (v.x + o2.x), 0.f);
        r.y = fmaxf(0.5f * (v.y + o2.y), 0.f);
        r.z = fmaxf(0.5f * (v.z + o2.z), 0.f);
        r.w = fmaxf(0.5f * (v.w + o2.w), 0.f);
        if (hshuf) {
            int g = d >> 4, m = d & 15;
            int ks = lane >> 3, q = (lane >> 1) & 3;
            int cell = ((g * 4 + ks) * 4 + q) * 16 + m;
            hshuf[cell * 2 + (lane & 1)] = pack_bf16x4(r.x, r.y, r.z, r.w);
        }
        if (pdots) {
            float4 wv = ((const float4*)fw)[lane];
            float pd = r.x * wv.x + r.y * wv.y + r.z * wv.z + r.w * wv.w;
            #pragma unroll
            for (int o = 16; o; o >>= 1) pd += __shfl_xor(pd, o);
            if (lane == 0) pdots[d] = pd;
        }
    }
}

// ---------------------------------------------------------------------------
// Final pooling: segment-sum of per-node dots (batch is sorted)
// ---------------------------------------------------------------------------

__global__ __launch_bounds__(256) void segpool_kernel(const float* __restrict__ p,
                                                      const int* __restrict__ batch,
                                                      float* __restrict__ y, int N, int G) {
    __shared__ float bins[128];
    int t = threadIdx.x;
    if (t < G) bins[t] = 0.f;
    __syncthreads();
    int per = (N + gridDim.x - 1) / gridDim.x;
    int lo = blockIdx.x * per;
    int hi = min(lo + per, N);
    float acc = 0.f;
    int key = -1;
    for (int i = lo + t; i < hi; i += 256) {
        int k = batch[i];
        float v = p[i];
        if (k != key) {
            if (key >= 0) atomicAdd(&bins[key], acc);
            key = k;
            acc = 0.f;
        }
        acc += v;
    }
    if (key >= 0) atomicAdd(&bins[key], acc);
    __syncthreads();
    if (t < G && bins[t] != 0.f) atomicAdd(&y[t], bins[t]);
}

// ---------------------------------------------------------------------------
// Host side
// ---------------------------------------------------------------------------

extern "C" void kernel_launch(void* const* d_in, const int* in_sizes, int n_in,
                              void* d_out, int out_size, void* d_ws, size_t ws_size,
                              hipStream_t stream) {
    const float* x     = (const float*)d_in[0];
    const int*   ei    = (const int*)d_in[1];
    const float* eattr = (const float*)d_in[2];
    const int*   batch = (const int*)d_in[3];
    const float* fw    = (const float*)d_in[16];
    const float* fb    = (const float*)d_in[17];
    float* y = (float*)d_out;

    const int N = in_sizes[0] / DD;     // 50000  (divisible by 16)
    const int E = in_sizes[1] / 2;      // 800000
    const int G = out_size;             // 128

    const int* src = ei;
    const int* dst = ei + E;

    char* ws = (char*)d_ws;
    size_t off = 0;
    auto carve = [&](size_t bytes) {
        char* p = ws + off;
        off += (bytes + 255) & ~(size_t)255;
        return p;
    };
    uint2*  xhb     = (uint2*)carve((size_t)N * 256 * 2);   // bf16 features [N][256]
    uint2*  S0      = (uint2*)carve((size_t)N * 128 * 2);   // shuffled bf16 A (ping)
    uint2*  S1      = (uint2*)carve((size_t)N * 128 * 2);   // shuffled bf16 A (pong)
    unsigned short* Bs = (unsigned short*)carve((size_t)3 * 128 * 256 * 2);
    float2* ae0     = (float2*)carve((size_t)E * 2 * 4);
    float2* ae1     = (float2*)carve((size_t)E * 2 * 4);
    float2* ae2     = (float2*)carve((size_t)E * 2 * 4);
    float*  aiaj    = (float*)carve((size_t)N * 4 * 4);
    int*    row_off = (int*)carve((size_t)(N + 1) * 4);
    int*    cnt     = (int*)carve((size_t)N * 4);
    int*    rank    = (int*)carve((size_t)E * 4);
    int*    csr_src = (int*)carve((size_t)E * 4);
    int*    perm    = (int*)carve((size_t)E * 4);
    float*  pdots   = (float*)carve((size_t)N * 4);
    int*    bsum    = (int*)carve((size_t)256 * 4);

    const int NB = (N + 1023) / 1024;   // 49 <= 64
    const int Ngroups = N / 16;         // 3125
    const int eb = (E + 255) / 256;     // 3125

    // ---- CSR build: rank (1 atomic pass) -> scans -> perm (no atomics) ----
    hipMemsetAsync(cnt, 0, (size_t)N * 4, stream);
    rank_kernel<<<eb, 256, 0, stream>>>(dst, cnt, rank, E);
    scan1<<<NB, 256, 0, stream>>>(cnt, bsum, N, y, fb);
    scan2<<<1, 64, 0, stream>>>(bsum, NB, row_off + N);
    scan3<<<NB, 256, 0, stream>>>(cnt, bsum, row_off, N);
    perm_kernel<<<eb, 256, 0, stream>>>(dst, rank, row_off, perm, E);

    // ---- fused prep: edge transform (by CSR pos) + pack_a0 + pack_w3 ----
    const int ebA = (N * 32 + 255) / 256;
    const int ebW = (3 * 128 * 64 + 255) / 256;
    prep_fused<<<eb + ebA + ebW, 256, 0, stream>>>(
        eattr, src, perm,
        (const float*)d_in[5], (const float*)d_in[6],
        (const float*)d_in[9], (const float*)d_in[10],
        (const float*)d_in[13], (const float*)d_in[14],
        csr_src, ae0, ae1, ae2, E, eb,
        x, S0, N, ebA,
        (const float*)d_in[4], (const float*)d_in[8], (const float*)d_in[12], Bs);

    // ---- 3 GAT layers ----
    int gemm_blocks = (Ngroups * 2 + 3) / 4;
    float2* aes[3] = {ae0, ae1, ae2};
    uint2* Ain[3]  = {S0, S1, S0};
    uint2* Aout[3] = {S1, S0, nullptr};

    for (int l = 0; l < 3; ++l) {
        const float* att  = (const float*)d_in[6 + 4 * l];
        const float* bias = (const float*)d_in[7 + 4 * l];
        const short8* Bl  = (const short8*)(Bs + (size_t)l * 128 * 256);

        gemm_mfma<<<gemm_blocks, 256, 0, stream>>>((const short8*)Ain[l], Bl,
                                                   bias, att, xhb, aiaj, Ngroups);
        aggregate<<<N, 64, 0, stream>>>(xhb, aiaj, aes[l], row_off, csr_src,
                                        Aout[l], fw, (l == 2) ? pdots : nullptr, N);
    }

    // ---- pooling ----
    segpool_kernel<<<128, 256, 0, stream>>>(pdots, batch, y, N, G);
}

// Round 10
// 441.739 us; speedup vs baseline: 1.4820x; 1.0211x over previous
//
#include <hip/hip_runtime.h>
#include <hip/hip_bf16.h>

// Problem constants (match reference)
#define DD 128      // feature dim
#define AA 4        // edge attr dim
#define HH 2        // heads

typedef short short8 __attribute__((ext_vector_type(8)));
typedef float f32x4 __attribute__((ext_vector_type(4)));

// bf16 pack/unpack (RNE)
__device__ inline unsigned short f2bf(float f) {
    unsigned u = __float_as_uint(f);
    unsigned r = (u + 0x7fffu + ((u >> 16) & 1u)) >> 16;
    return (unsigned short)r;
}
__device__ inline float4 unpack_bf16x4(uint2 v) {
    float4 r;
    r.x = __uint_as_float(v.x << 16);
    r.y = __uint_as_float(v.x & 0xffff0000u);
    r.z = __uint_as_float(v.y << 16);
    r.w = __uint_as_float(v.y & 0xffff0000u);
    return r;
}
__device__ inline uint2 pack_bf16x4(float a, float b, float c, float d) {
    uint2 p;
    p.x = (unsigned)f2bf(a) | ((unsigned)f2bf(b) << 16);
    p.y = (unsigned)f2bf(c) | ((unsigned)f2bf(d) << 16);
    return p;
}

// ---------------------------------------------------------------------------
// CSR build, pass 1: histogram + per-edge rank in ONE atomic pass.
// ---------------------------------------------------------------------------

__global__ void rank_kernel(const int* __restrict__ dst, int* __restrict__ cnt,
                            int* __restrict__ rank, int E) {
    int e = blockIdx.x * blockDim.x + threadIdx.x;
    if (e < E) rank[e] = atomicAdd(&cnt[dst[e]], 1);
}

// scan1: per-1024-chunk sums; block 0 also inits y = fb
__global__ __launch_bounds__(256) void scan1(const int* __restrict__ cnt,
                                             int* __restrict__ bsum, int N,
                                             float* __restrict__ y,
                                             const float* __restrict__ fb) {
    __shared__ int wsh[4];
    int b = blockIdx.x, t = threadIdx.x;
    int lane = t & 63, w = t >> 6;
    if (b == 0 && t < 128) y[t] = fb[0];
    int base = b * 1024;
    int v = 0;
    #pragma unroll
    for (int i = 0; i < 4; ++i) {
        int idx = base + i * 256 + t;
        v += (idx < N) ? cnt[idx] : 0;
    }
    #pragma unroll
    for (int o = 32; o; o >>= 1) v += __shfl_xor(v, o);
    if (lane == 0) wsh[w] = v;
    __syncthreads();
    if (t == 0) bsum[b] = wsh[0] + wsh[1] + wsh[2] + wsh[3];
}

__global__ __launch_bounds__(64) void scan2(int* __restrict__ bsum, int NB,
                                            int* __restrict__ total) {
    int t = threadIdx.x;
    int v = (t < NB) ? bsum[t] : 0;
    int x = v;
    #pragma unroll
    for (int o = 1; o < 64; o <<= 1) {
        int u = __shfl_up(x, o);
        if (t >= o) x += u;
    }
    if (t < NB) bsum[t] = x - v;
    if (t == 63) *total = x;
}

__global__ __launch_bounds__(256) void scan3(const int* __restrict__ cnt,
                                             const int* __restrict__ bsum,
                                             int* __restrict__ row_off, int N) {
    __shared__ int wtot[4];
    __shared__ int carry;
    int b = blockIdx.x, t = threadIdx.x;
    int lane = t & 63, w = t >> 6;
    if (t == 0) carry = bsum[b];
    __syncthreads();
    int base = b * 1024;
    #pragma unroll
    for (int it = 0; it < 4; ++it) {
        int idx = base + it * 256 + t;
        int v = (idx < N) ? cnt[idx] : 0;
        int x = v;
        #pragma unroll
        for (int o = 1; o < 64; o <<= 1) {
            int u = __shfl_up(x, o);
            if (lane >= o) x += u;
        }
        if (lane == 63) wtot[w] = x;
        __syncthreads();
        int woff = 0;
        for (int i = 0; i < w; ++i) woff += wtot[i];
        int c = carry;
        __syncthreads();
        if (t == 255) carry = c + woff + x;
        int ex = c + woff + x - v;
        if (idx < N) row_off[idx] = ex;
        __syncthreads();
    }
}

// CSR build, pass 2: p = row_off[dst] + rank  (no atomics, 1 random 4B write)
__global__ void perm_kernel(const int* __restrict__ dst, const int* __restrict__ rank,
                            const int* __restrict__ row_off, int* __restrict__ perm, int E) {
    int e = blockIdx.x * blockDim.x + threadIdx.x;
    if (e >= E) return;
    perm[row_off[dst[e]] + rank[e]] = e;
}

// ---------------------------------------------------------------------------
// Fused edge transform (all 3 layers, CSR-ordered, write-coalesced) +
// pack_a0 + pack_w3 in one kernel via blockIdx range split.
// ---------------------------------------------------------------------------

__device__ inline void edge_stage(const float4& ev, const float* __restrict__ linE,
                                  const float* __restrict__ att, float2& ae, float4& enext) {
    float eh[8];
    #pragma unroll
    for (int c = 0; c < 8; ++c)
        eh[c] = ev.x * linE[c] + ev.y * linE[8 + c] + ev.z * linE[16 + c] + ev.w * linE[24 + c];
    float a0 = 0.f, a1 = 0.f;
    #pragma unroll
    for (int a = 0; a < 4; ++a) {
        a0 += eh[a]     * att[2 * DD + a];
        a1 += eh[4 + a] * att[(2 * DD + AA) + 2 * DD + a];
    }
    ae.x = a0; ae.y = a1;
    enext.x = fmaxf(0.5f * (eh[0] + eh[4]), 0.f);
    enext.y = fmaxf(0.5f * (eh[1] + eh[5]), 0.f);
    enext.z = fmaxf(0.5f * (eh[2] + eh[6]), 0.f);
    enext.w = fmaxf(0.5f * (eh[3] + eh[7]), 0.f);
}

__global__ __launch_bounds__(256) void prep_fused(
        const float* __restrict__ ein, const int* __restrict__ src,
        const int* __restrict__ perm,
        const float* __restrict__ linE0, const float* __restrict__ att0,
        const float* __restrict__ linE1, const float* __restrict__ att1,
        const float* __restrict__ linE2, const float* __restrict__ att2,
        int* __restrict__ csr_src,
        float2* __restrict__ ae0, float2* __restrict__ ae1, float2* __restrict__ ae2,
        int E, int ebE,
        const float* __restrict__ X, uint2* __restrict__ As, int N, int ebA,
        const float* __restrict__ W0, const float* __restrict__ W1,
        const float* __restrict__ W2, unsigned short* __restrict__ Bs) {
    int b = blockIdx.x;
    if (b < ebE) {
        int p = b * 256 + threadIdx.x;
        if (p >= E) return;
        int e = perm[p];                       // coalesced
        csr_src[p] = src[e];                   // random read, coalesced write
        float4 ev = ((const float4*)ein)[e];   // random 16B read (L3-resident)
        float2 ae; float4 en;
        edge_stage(ev, linE0, att0, ae, en); ae0[p] = ae;
        edge_stage(en, linE1, att1, ae, ev); ae1[p] = ae;
        edge_stage(ev, linE2, att2, ae, en); ae2[p] = ae;
    } else if (b < ebE + ebA) {
        int t = (b - ebE) * 256 + threadIdx.x;
        if (t >= N * 32) return;
        int r = t >> 5, kq4 = t & 31;
        float4 v = ((const float4*)X)[t];
        int g = r >> 4, m = r & 15;
        int ks = kq4 >> 3, q = (kq4 >> 1) & 3;
        int cell = ((g * 4 + ks) * 4 + q) * 16 + m;
        As[cell * 2 + (kq4 & 1)] = pack_bf16x4(v.x, v.y, v.z, v.w);
    } else {
        int t = (b - ebE - ebA) * 256 + threadIdx.x;
        if (t >= 3 * 128 * 64) return;
        int l = t / (128 * 64);
        int r = t - l * (128 * 64);
        const float* W = (l == 0) ? W0 : (l == 1) ? W1 : W2;
        unsigned short* B = Bs + (size_t)l * 128 * 256;
        int k = r >> 6, c4g = r & 63;
        float4 v = ((const float4*)W)[r];
        int ct = c4g >> 2, n0 = (c4g & 3) * 4;
        int ks = k >> 5, q = (k >> 3) & 3, j = k & 7;
        int cellbase = ((ct * 4 + ks) * 4 + q) * 16 + n0;
        B[(cellbase + 0) * 8 + j] = f2bf(v.x);
        B[(cellbase + 1) * 8 + j] = f2bf(v.y);
        B[(cellbase + 2) * 8 + j] = f2bf(v.z);
        B[(cellbase + 3) * 8 + j] = f2bf(v.w);
    }
}

// ---------------------------------------------------------------------------
// MFMA GEMM + fused epilogue. One wave per (16-row group, head-half).
// ---------------------------------------------------------------------------

__global__ __launch_bounds__(256) void gemm_mfma(const short8* __restrict__ As,
                                                 const short8* __restrict__ Bs,
                                                 const float* __restrict__ bias,
                                                 const float* __restrict__ att,
                                                 uint2* __restrict__ xhb,
                                                 float* __restrict__ aiaj, int Ngroups) {
    __shared__ __align__(16) unsigned short sh[4][16 * 132];
    int w = threadIdx.x >> 6;
    int flat = blockIdx.x * 4 + w;
    int wid = flat >> 1, half = flat & 1;
    int lane = threadIdx.x & 63;
    if (wid >= Ngroups) return;
    int q = lane >> 4, m = lane & 15;

    const short8* Ag = As + (size_t)wid * 256;
    f32x4 acc[8];
    #pragma unroll
    for (int c8 = 0; c8 < 8; ++c8) acc[c8] = (f32x4){0.f, 0.f, 0.f, 0.f};

    #pragma unroll
    for (int ks = 0; ks < 4; ++ks) {
        short8 a = Ag[ks * 64 + lane];
        #pragma unroll
        for (int c8 = 0; c8 < 8; ++c8) {
            short8 b = Bs[(half * 8 + c8) * 256 + ks * 64 + lane];
            acc[c8] = __builtin_amdgcn_mfma_f32_16x16x32_bf16(a, b, acc[c8], 0, 0, 0);
        }
    }

    const float* atth = att + half * (2 * DD + AA);
    float ai[4] = {}, aj[4] = {};
    #pragma unroll
    for (int c8 = 0; c8 < 8; ++c8) {
        int col = c8 * 16 + m;
        float aS = atth[col];
        float aD = atth[DD + col];
        float bv = bias[(half * 8 + c8) * 16 + m];
        #pragma unroll
        for (int reg = 0; reg < 4; ++reg) {
            float val = acc[c8][reg] + bv;
            sh[w][(q * 4 + reg) * 132 + col] = f2bf(val);
            ai[reg] += val * aS;
            aj[reg] += val * aD;
        }
    }
    #pragma unroll
    for (int o = 1; o < 16; o <<= 1) {
        #pragma unroll
        for (int reg = 0; reg < 4; ++reg) {
            ai[reg] += __shfl_xor(ai[reg], o);
            aj[reg] += __shfl_xor(aj[reg], o);
        }
    }
    if (m == 0) {
        #pragma unroll
        for (int reg = 0; reg < 4; ++reg) {
            int row = wid * 16 + q * 4 + reg;
            aiaj[row * 4 + half] = ai[reg];
            aiaj[row * 4 + 2 + half] = aj[reg];
        }
    }
    #pragma unroll
    for (int r2 = 0; r2 < 8; ++r2) {
        int row = r2 * 2 + (lane >> 5);
        uint2 v = *(const uint2*)&sh[w][row * 132 + (lane & 31) * 4];
        xhb[(size_t)(wid * 16 + row) * 64 + half * 32 + (lane & 31)] = v;
    }
}

// ---------------------------------------------------------------------------
// Aggregation: 4 independent waves per 256-thread block, each wave owns one
// dst node (wave-private LDS, barrier-free). Doubles resident waves/CU vs
// 64-thread blocks (workgroup-slot limit). Single-pass softmax; bf16 payload.
// ---------------------------------------------------------------------------

__global__ __launch_bounds__(256) void aggregate(const uint2* __restrict__ xhb,
                                                 const float* __restrict__ aiaj,
                                                 const float2* __restrict__ ae,
                                                 const int* __restrict__ row_off,
                                                 const int* __restrict__ csr_src,
                                                 uint2* __restrict__ hshuf,
                                                 const float* __restrict__ fw,
                                                 float* __restrict__ pdots, int N) {
    int w = threadIdx.x >> 6;
    int d = blockIdx.x * 4 + w;
    int lane = threadIdx.x & 63;
    if (d >= N) return;
    int s0 = row_off[d], s1 = row_off[d + 1];
    int deg = s1 - s0;
    const float2* aiaj2 = (const float2*)aiaj;
    float2 ajv = aiaj2[d * 2 + 1];   // (aj0, aj1)

    __shared__ float lex[4][64][2];
    __shared__ int lsrc[4][64];
    float4 acc = {0.f, 0.f, 0.f, 0.f};
    float den0 = 0.f, den1 = 0.f;
    int head = lane >> 5;

    for (int c = 0; c < deg; c += 64) {
        int n = min(64, deg - c);
        if (lane < n) {
            int p = s0 + c + lane;
            int s = csr_src[p];
            float2 aiv = aiaj2[s * 2];
            float2 aev = ae[p];
            float a0 = aiv.x + ajv.x + aev.x; a0 = a0 > 0.f ? a0 : 0.2f * a0;
            float a1 = aiv.y + ajv.y + aev.y; a1 = a1 > 0.f ? a1 : 0.2f * a1;
            float e0 = __expf(a0), e1 = __expf(a1);
            den0 += e0; den1 += e1;
            lex[w][lane][0] = e0; lex[w][lane][1] = e1;
            lsrc[w][lane] = s;
        }
        #pragma unroll 8
        for (int j = 0; j < n; ++j) {
            float wgt = lex[w][j][head];
            float4 xv = unpack_bf16x4(xhb[(size_t)lsrc[w][j] * 64 + lane]);
            acc.x += wgt * xv.x; acc.y += wgt * xv.y;
            acc.z += wgt * xv.z; acc.w += wgt * xv.w;
        }
    }

    #pragma unroll
    for (int o = 32; o; o >>= 1) {
        den0 += __shfl_xor(den0, o);
        den1 += __shfl_xor(den1, o);
    }
    float den = head ? den1 : den0;
    if (deg == 0) den = 1.0f;
    float inv = 1.0f / den;

    float4 xd = unpack_bf16x4(xhb[(size_t)d * 64 + lane]);
    float4 v;
    v.x = acc.x * inv + xd.x;
    v.y = acc.y * inv + xd.y;
    v.z = acc.z * inv + xd.z;
    v.w = acc.w * inv + xd.w;
    float4 o2;
    o2.x = __shfl_xor(v.x, 32);
    o2.y = __shfl_xor(v.y, 32);
    o2.z = __shfl_xor(v.z, 32);
    o2.w = __shfl_xor(v.w, 32);
    if (lane < 32) {
        float4 r;
        r.x = fmaxf(0.5f * (v.x + o2.x), 0.f);
        r.y = fmaxf(0.5f * (v.y + o2.y), 0.f);
        r.z = fmaxf(0.5f * (v.z + o2.z), 0.f);
        r.w = fmaxf(0.5f * (v.w + o2.w), 0.f);
        if (hshuf) {
            int g = d >> 4, m = d & 15;
            int ks = lane >> 3, q = (lane >> 1) & 3;
            int cell = ((g * 4 + ks) * 4 + q) * 16 + m;
            hshuf[cell * 2 + (lane & 1)] = pack_bf16x4(r.x, r.y, r.z, r.w);
        }
        if (pdots) {
            float4 wv = ((const float4*)fw)[lane];
            float pd = r.x * wv.x + r.y * wv.y + r.z * wv.z + r.w * wv.w;
            #pragma unroll
            for (int o = 16; o; o >>= 1) pd += __shfl_xor(pd, o);
            if (lane == 0) pdots[d] = pd;
        }
    }
}

// ---------------------------------------------------------------------------
// Final pooling: segment-sum of per-node dots (batch is sorted)
// ---------------------------------------------------------------------------

__global__ __launch_bounds__(256) void segpool_kernel(const float* __restrict__ p,
                                                      const int* __restrict__ batch,
                                                      float* __restrict__ y, int N, int G) {
    __shared__ float bins[128];
    int t = threadIdx.x;
    if (t < G) bins[t] = 0.f;
    __syncthreads();
    int per = (N + gridDim.x - 1) / gridDim.x;
    int lo = blockIdx.x * per;
    int hi = min(lo + per, N);
    float acc = 0.f;
    int key = -1;
    for (int i = lo + t; i < hi; i += 256) {
        int k = batch[i];
        float v = p[i];
        if (k != key) {
            if (key >= 0) atomicAdd(&bins[key], acc);
            key = k;
            acc = 0.f;
        }
        acc += v;
    }
    if (key >= 0) atomicAdd(&bins[key], acc);
    __syncthreads();
    if (t < G && bins[t] != 0.f) atomicAdd(&y[t], bins[t]);
}

// ---------------------------------------------------------------------------
// Host side
// ---------------------------------------------------------------------------

extern "C" void kernel_launch(void* const* d_in, const int* in_sizes, int n_in,
                              void* d_out, int out_size, void* d_ws, size_t ws_size,
                              hipStream_t stream) {
    const float* x     = (const float*)d_in[0];
    const int*   ei    = (const int*)d_in[1];
    const float* eattr = (const float*)d_in[2];
    const int*   batch = (const int*)d_in[3];
    const float* fw    = (const float*)d_in[16];
    const float* fb    = (const float*)d_in[17];
    float* y = (float*)d_out;

    const int N = in_sizes[0] / DD;     // 50000  (divisible by 16)
    const int E = in_sizes[1] / 2;      // 800000
    const int G = out_size;             // 128

    const int* src = ei;
    const int* dst = ei + E;

    char* ws = (char*)d_ws;
    size_t off = 0;
    auto carve = [&](size_t bytes) {
        char* p = ws + off;
        off += (bytes + 255) & ~(size_t)255;
        return p;
    };
    uint2*  xhb     = (uint2*)carve((size_t)N * 256 * 2);   // bf16 features [N][256]
    uint2*  S0      = (uint2*)carve((size_t)N * 128 * 2);   // shuffled bf16 A (ping)
    uint2*  S1      = (uint2*)carve((size_t)N * 128 * 2);   // shuffled bf16 A (pong)
    unsigned short* Bs = (unsigned short*)carve((size_t)3 * 128 * 256 * 2);
    float2* ae0     = (float2*)carve((size_t)E * 2 * 4);
    float2* ae1     = (float2*)carve((size_t)E * 2 * 4);
    float2* ae2     = (float2*)carve((size_t)E * 2 * 4);
    float*  aiaj    = (float*)carve((size_t)N * 4 * 4);
    int*    row_off = (int*)carve((size_t)(N + 1) * 4);
    int*    cnt     = (int*)carve((size_t)N * 4);
    int*    rank    = (int*)carve((size_t)E * 4);
    int*    csr_src = (int*)carve((size_t)E * 4);
    int*    perm    = (int*)carve((size_t)E * 4);
    float*  pdots   = (float*)carve((size_t)N * 4);
    int*    bsum    = (int*)carve((size_t)256 * 4);

    const int NB = (N + 1023) / 1024;   // 49 <= 64
    const int Ngroups = N / 16;         // 3125
    const int eb = (E + 255) / 256;     // 3125

    // ---- CSR build: rank (1 atomic pass) -> scans -> perm (no atomics) ----
    hipMemsetAsync(cnt, 0, (size_t)N * 4, stream);
    rank_kernel<<<eb, 256, 0, stream>>>(dst, cnt, rank, E);
    scan1<<<NB, 256, 0, stream>>>(cnt, bsum, N, y, fb);
    scan2<<<1, 64, 0, stream>>>(bsum, NB, row_off + N);
    scan3<<<NB, 256, 0, stream>>>(cnt, bsum, row_off, N);
    perm_kernel<<<eb, 256, 0, stream>>>(dst, rank, row_off, perm, E);

    // ---- fused prep: edge transform (by CSR pos) + pack_a0 + pack_w3 ----
    const int ebA = (N * 32 + 255) / 256;
    const int ebW = (3 * 128 * 64 + 255) / 256;
    prep_fused<<<eb + ebA + ebW, 256, 0, stream>>>(
        eattr, src, perm,
        (const float*)d_in[5], (const float*)d_in[6],
        (const float*)d_in[9], (const float*)d_in[10],
        (const float*)d_in[13], (const float*)d_in[14],
        csr_src, ae0, ae1, ae2, E, eb,
        x, S0, N, ebA,
        (const float*)d_in[4], (const float*)d_in[8], (const float*)d_in[12], Bs);

    // ---- 3 GAT layers ----
    int gemm_blocks = (Ngroups * 2 + 3) / 4;
    int agg_blocks = (N + 3) / 4;
    float2* aes[3] = {ae0, ae1, ae2};
    uint2* Ain[3]  = {S0, S1, S0};
    uint2* Aout[3] = {S1, S0, nullptr};

    for (int l = 0; l < 3; ++l) {
        const float* att  = (const float*)d_in[6 + 4 * l];
        const float* bias = (const float*)d_in[7 + 4 * l];
        const short8* Bl  = (const short8*)(Bs + (size_t)l * 128 * 256);

        gemm_mfma<<<gemm_blocks, 256, 0, stream>>>((const short8*)Ain[l], Bl,
                                                   bias, att, xhb, aiaj, Ngroups);
        aggregate<<<agg_blocks, 256, 0, stream>>>(xhb, aiaj, aes[l], row_off, csr_src,
                                                  Aout[l], fw, (l == 2) ? pdots : nullptr, N);
    }

    // ---- pooling ----
    segpool_kernel<<<128, 256, 0, stream>>>(pdots, batch, y, N, G);
}

// Round 11
// 433.566 us; speedup vs baseline: 1.5099x; 1.0188x over previous
//
#include <hip/hip_runtime.h>
#include <hip/hip_bf16.h>

// Problem constants (match reference)
#define DD 128      // feature dim
#define AA 4        // edge attr dim
#define HH 2        // heads

typedef short short8 __attribute__((ext_vector_type(8)));
typedef float f32x4 __attribute__((ext_vector_type(4)));

// bf16 pack/unpack (RNE)
__device__ inline unsigned short f2bf(float f) {
    unsigned u = __float_as_uint(f);
    unsigned r = (u + 0x7fffu + ((u >> 16) & 1u)) >> 16;
    return (unsigned short)r;
}
__device__ inline float4 unpack_bf16x4(uint2 v) {
    float4 r;
    r.x = __uint_as_float(v.x << 16);
    r.y = __uint_as_float(v.x & 0xffff0000u);
    r.z = __uint_as_float(v.y << 16);
    r.w = __uint_as_float(v.y & 0xffff0000u);
    return r;
}
__device__ inline uint2 pack_bf16x4(float a, float b, float c, float d) {
    uint2 p;
    p.x = (unsigned)f2bf(a) | ((unsigned)f2bf(b) << 16);
    p.y = (unsigned)f2bf(c) | ((unsigned)f2bf(d) << 16);
    return p;
}

// ---------------------------------------------------------------------------
// CSR build, pass 1: histogram + per-edge rank in ONE atomic pass.
// ---------------------------------------------------------------------------

__global__ void rank_kernel(const int* __restrict__ dst, int* __restrict__ cnt,
                            int* __restrict__ rank, int E) {
    int e = blockIdx.x * blockDim.x + threadIdx.x;
    if (e < E) rank[e] = atomicAdd(&cnt[dst[e]], 1);
}

// scan1: per-1024-chunk sums; block 0 also inits y = fb
__global__ __launch_bounds__(256) void scan1(const int* __restrict__ cnt,
                                             int* __restrict__ bsum, int N,
                                             float* __restrict__ y,
                                             const float* __restrict__ fb) {
    __shared__ int wsh[4];
    int b = blockIdx.x, t = threadIdx.x;
    int lane = t & 63, w = t >> 6;
    if (b == 0 && t < 128) y[t] = fb[0];
    int base = b * 1024;
    int v = 0;
    #pragma unroll
    for (int i = 0; i < 4; ++i) {
        int idx = base + i * 256 + t;
        v += (idx < N) ? cnt[idx] : 0;
    }
    #pragma unroll
    for (int o = 32; o; o >>= 1) v += __shfl_xor(v, o);
    if (lane == 0) wsh[w] = v;
    __syncthreads();
    if (t == 0) bsum[b] = wsh[0] + wsh[1] + wsh[2] + wsh[3];
}

// scan3: final per-element exclusive prefix. Each block wave-scans the raw
// chunk sums itself (NB <= 64) — no separate scan2 kernel.
__global__ __launch_bounds__(256) void scan3(const int* __restrict__ cnt,
                                             const int* __restrict__ bsum,
                                             int* __restrict__ row_off,
                                             int N, int NB, int E) {
    __shared__ int wtot[4];
    __shared__ int carry;
    int b = blockIdx.x, t = threadIdx.x;
    int lane = t & 63, w = t >> 6;
    if (w == 0) {
        int v = (lane < NB) ? bsum[lane] : 0;
        int x = v;
        #pragma unroll
        for (int o = 1; o < 64; o <<= 1) {
            int u = __shfl_up(x, o);
            if (lane >= o) x += u;
        }
        int base = (b == 0) ? 0 : __shfl(x, b - 1);  // sum of bsum[0..b)
        if (lane == 0) carry = base;
    }
    if (b == 0 && t == 0) row_off[N] = E;
    __syncthreads();
    int base = b * 1024;
    #pragma unroll
    for (int it = 0; it < 4; ++it) {
        int idx = base + it * 256 + t;
        int v = (idx < N) ? cnt[idx] : 0;
        int x = v;
        #pragma unroll
        for (int o = 1; o < 64; o <<= 1) {
            int u = __shfl_up(x, o);
            if (lane >= o) x += u;
        }
        if (lane == 63) wtot[w] = x;
        __syncthreads();
        int woff = 0;
        for (int i = 0; i < w; ++i) woff += wtot[i];
        int c = carry;
        __syncthreads();
        if (t == 255) carry = c + woff + x;
        int ex = c + woff + x - v;
        if (idx < N) row_off[idx] = ex;
        __syncthreads();
    }
}

// CSR build, pass 2: one random 8B write of (edge id, src) per edge.
__global__ void perm_kernel(const int* __restrict__ src, const int* __restrict__ dst,
                            const int* __restrict__ rank,
                            const int* __restrict__ row_off,
                            int2* __restrict__ perm2, int E) {
    int e = blockIdx.x * blockDim.x + threadIdx.x;
    if (e >= E) return;
    int2 v; v.x = e; v.y = src[e];
    perm2[row_off[dst[e]] + rank[e]] = v;
}

// ---------------------------------------------------------------------------
// Fused edge transform (all 3 layers, CSR-ordered, write-coalesced) +
// pack_a0 + pack_w3 in one kernel via blockIdx range split.
// ---------------------------------------------------------------------------

__device__ inline void edge_stage(const float4& ev, const float* __restrict__ linE,
                                  const float* __restrict__ att, float2& ae, float4& enext) {
    float eh[8];
    #pragma unroll
    for (int c = 0; c < 8; ++c)
        eh[c] = ev.x * linE[c] + ev.y * linE[8 + c] + ev.z * linE[16 + c] + ev.w * linE[24 + c];
    float a0 = 0.f, a1 = 0.f;
    #pragma unroll
    for (int a = 0; a < 4; ++a) {
        a0 += eh[a]     * att[2 * DD + a];
        a1 += eh[4 + a] * att[(2 * DD + AA) + 2 * DD + a];
    }
    ae.x = a0; ae.y = a1;
    enext.x = fmaxf(0.5f * (eh[0] + eh[4]), 0.f);
    enext.y = fmaxf(0.5f * (eh[1] + eh[5]), 0.f);
    enext.z = fmaxf(0.5f * (eh[2] + eh[6]), 0.f);
    enext.w = fmaxf(0.5f * (eh[3] + eh[7]), 0.f);
}

__global__ __launch_bounds__(256) void prep_fused(
        const float* __restrict__ ein, const int2* __restrict__ perm2,
        const float* __restrict__ linE0, const float* __restrict__ att0,
        const float* __restrict__ linE1, const float* __restrict__ att1,
        const float* __restrict__ linE2, const float* __restrict__ att2,
        float2* __restrict__ ae0, float2* __restrict__ ae1, float2* __restrict__ ae2,
        int E, int ebE,
        const float* __restrict__ X, uint2* __restrict__ As, int N, int ebA,
        const float* __restrict__ W0, const float* __restrict__ W1,
        const float* __restrict__ W2, unsigned short* __restrict__ Bs) {
    int b = blockIdx.x;
    if (b < ebE) {
        int p = b * 256 + threadIdx.x;
        if (p >= E) return;
        int e = perm2[p].x;                    // coalesced
        float4 ev = ((const float4*)ein)[e];   // random 16B read (L3-resident)
        float2 ae; float4 en;
        edge_stage(ev, linE0, att0, ae, en); ae0[p] = ae;
        edge_stage(en, linE1, att1, ae, ev); ae1[p] = ae;
        edge_stage(ev, linE2, att2, ae, en); ae2[p] = ae;
    } else if (b < ebE + ebA) {
        int t = (b - ebE) * 256 + threadIdx.x;
        if (t >= N * 32) return;
        int r = t >> 5, kq4 = t & 31;
        float4 v = ((const float4*)X)[t];
        int g = r >> 4, m = r & 15;
        int ks = kq4 >> 3, q = (kq4 >> 1) & 3;
        int cell = ((g * 4 + ks) * 4 + q) * 16 + m;
        As[cell * 2 + (kq4 & 1)] = pack_bf16x4(v.x, v.y, v.z, v.w);
    } else {
        int t = (b - ebE - ebA) * 256 + threadIdx.x;
        if (t >= 3 * 128 * 64) return;
        int l = t / (128 * 64);
        int r = t - l * (128 * 64);
        const float* W = (l == 0) ? W0 : (l == 1) ? W1 : W2;
        unsigned short* B = Bs + (size_t)l * 128 * 256;
        int k = r >> 6, c4g = r & 63;
        float4 v = ((const float4*)W)[r];
        int ct = c4g >> 2, n0 = (c4g & 3) * 4;
        int ks = k >> 5, q = (k >> 3) & 3, j = k & 7;
        int cellbase = ((ct * 4 + ks) * 4 + q) * 16 + n0;
        B[(cellbase + 0) * 8 + j] = f2bf(v.x);
        B[(cellbase + 1) * 8 + j] = f2bf(v.y);
        B[(cellbase + 2) * 8 + j] = f2bf(v.z);
        B[(cellbase + 3) * 8 + j] = f2bf(v.w);
    }
}

// ---------------------------------------------------------------------------
// MFMA GEMM + fused epilogue. One wave per (16-row group, head-half).
// ---------------------------------------------------------------------------

__global__ __launch_bounds__(256) void gemm_mfma(const short8* __restrict__ As,
                                                 const short8* __restrict__ Bs,
                                                 const float* __restrict__ bias,
                                                 const float* __restrict__ att,
                                                 uint2* __restrict__ xhb,
                                                 float* __restrict__ aiaj, int Ngroups) {
    __shared__ __align__(16) unsigned short sh[4][16 * 132];
    int w = threadIdx.x >> 6;
    int flat = blockIdx.x * 4 + w;
    int wid = flat >> 1, half = flat & 1;
    int lane = threadIdx.x & 63;
    if (wid >= Ngroups) return;
    int q = lane >> 4, m = lane & 15;

    const short8* Ag = As + (size_t)wid * 256;
    f32x4 acc[8];
    #pragma unroll
    for (int c8 = 0; c8 < 8; ++c8) acc[c8] = (f32x4){0.f, 0.f, 0.f, 0.f};

    #pragma unroll
    for (int ks = 0; ks < 4; ++ks) {
        short8 a = Ag[ks * 64 + lane];
        #pragma unroll
        for (int c8 = 0; c8 < 8; ++c8) {
            short8 b = Bs[(half * 8 + c8) * 256 + ks * 64 + lane];
            acc[c8] = __builtin_amdgcn_mfma_f32_16x16x32_bf16(a, b, acc[c8], 0, 0, 0);
        }
    }

    const float* atth = att + half * (2 * DD + AA);
    float ai[4] = {}, aj[4] = {};
    #pragma unroll
    for (int c8 = 0; c8 < 8; ++c8) {
        int col = c8 * 16 + m;
        float aS = atth[col];
        float aD = atth[DD + col];
        float bv = bias[(half * 8 + c8) * 16 + m];
        #pragma unroll
        for (int reg = 0; reg < 4; ++reg) {
            float val = acc[c8][reg] + bv;
            sh[w][(q * 4 + reg) * 132 + col] = f2bf(val);
            ai[reg] += val * aS;
            aj[reg] += val * aD;
        }
    }
    #pragma unroll
    for (int o = 1; o < 16; o <<= 1) {
        #pragma unroll
        for (int reg = 0; reg < 4; ++reg) {
            ai[reg] += __shfl_xor(ai[reg], o);
            aj[reg] += __shfl_xor(aj[reg], o);
        }
    }
    if (m == 0) {
        #pragma unroll
        for (int reg = 0; reg < 4; ++reg) {
            int row = wid * 16 + q * 4 + reg;
            aiaj[row * 4 + half] = ai[reg];
            aiaj[row * 4 + 2 + half] = aj[reg];
        }
    }
    #pragma unroll
    for (int r2 = 0; r2 < 8; ++r2) {
        int row = r2 * 2 + (lane >> 5);
        uint2 v = *(const uint2*)&sh[w][row * 132 + (lane & 31) * 4];
        xhb[(size_t)(wid * 16 + row) * 64 + half * 32 + (lane & 31)] = v;
    }
}

// ---------------------------------------------------------------------------
// Aggregation: 4 independent waves per 256-thread block, each wave owns one
// dst node (wave-private LDS, barrier-free). Single-pass softmax; bf16
// payload; skip-row load hoisted above the gather loop.
// ---------------------------------------------------------------------------

__global__ __launch_bounds__(256) void aggregate(const uint2* __restrict__ xhb,
                                                 const float* __restrict__ aiaj,
                                                 const float2* __restrict__ ae,
                                                 const int* __restrict__ row_off,
                                                 const int2* __restrict__ perm2,
                                                 uint2* __restrict__ hshuf,
                                                 const float* __restrict__ fw,
                                                 float* __restrict__ pdots, int N) {
    int w = threadIdx.x >> 6;
    int d = blockIdx.x * 4 + w;
    int lane = threadIdx.x & 63;
    if (d >= N) return;
    int s0 = row_off[d], s1 = row_off[d + 1];
    int deg = s1 - s0;
    const float2* aiaj2 = (const float2*)aiaj;
    float2 ajv = aiaj2[d * 2 + 1];   // (aj0, aj1)
    float4 xd = unpack_bf16x4(xhb[(size_t)d * 64 + lane]);   // skip row (early)

    __shared__ float lex[4][64][2];
    __shared__ int lsrc[4][64];
    float4 acc = {0.f, 0.f, 0.f, 0.f};
    float den0 = 0.f, den1 = 0.f;
    int head = lane >> 5;

    for (int c = 0; c < deg; c += 64) {
        int n = min(64, deg - c);
        if (lane < n) {
            int p = s0 + c + lane;
            int s = perm2[p].y;
            float2 aiv = aiaj2[s * 2];
            float2 aev = ae[p];
            float a0 = aiv.x + ajv.x + aev.x; a0 = a0 > 0.f ? a0 : 0.2f * a0;
            float a1 = aiv.y + ajv.y + aev.y; a1 = a1 > 0.f ? a1 : 0.2f * a1;
            float e0 = __expf(a0), e1 = __expf(a1);
            den0 += e0; den1 += e1;
            lex[w][lane][0] = e0; lex[w][lane][1] = e1;
            lsrc[w][lane] = s;
        }
        #pragma unroll 8
        for (int j = 0; j < n; ++j) {
            float wgt = lex[w][j][head];
            float4 xv = unpack_bf16x4(xhb[(size_t)lsrc[w][j] * 64 + lane]);
            acc.x += wgt * xv.x; acc.y += wgt * xv.y;
            acc.z += wgt * xv.z; acc.w += wgt * xv.w;
        }
    }

    #pragma unroll
    for (int o = 32; o; o >>= 1) {
        den0 += __shfl_xor(den0, o);
        den1 += __shfl_xor(den1, o);
    }
    float den = head ? den1 : den0;
    if (deg == 0) den = 1.0f;
    float inv = 1.0f / den;

    float4 v;
    v.x = acc.x * inv + xd.x;
    v.y = acc.y * inv + xd.y;
    v.z = acc.z * inv + xd.z;
    v.w = acc.w * inv + xd.w;
    float4 o2;
    o2.x = __shfl_xor(v.x, 32);
    o2.y = __shfl_xor(v.y, 32);
    o2.z = __shfl_xor(v.z, 32);
    o2.w = __shfl_xor(v.w, 32);
    if (lane < 32) {
        float4 r;
        r.x = fmaxf(0.5f * (v.x + o2.x), 0.f);
        r.y = fmaxf(0.5f * (v.y + o2.y), 0.f);
        r.z = fmaxf(0.5f * (v.z + o2.z), 0.f);
        r.w = fmaxf(0.5f * (v.w + o2.w), 0.f);
        if (hshuf) {
            int g = d >> 4, m = d & 15;
            int ks = lane >> 3, q = (lane >> 1) & 3;
            int cell = ((g * 4 + ks) * 4 + q) * 16 + m;
            hshuf[cell * 2 + (lane & 1)] = pack_bf16x4(r.x, r.y, r.z, r.w);
        }
        if (pdots) {
            float4 wv = ((const float4*)fw)[lane];
            float pd = r.x * wv.x + r.y * wv.y + r.z * wv.z + r.w * wv.w;
            #pragma unroll
            for (int o = 16; o; o >>= 1) pd += __shfl_xor(pd, o);
            if (lane == 0) pdots[d] = pd;
        }
    }
}

// ---------------------------------------------------------------------------
// Final pooling: segment-sum of per-node dots (batch is sorted)
// ---------------------------------------------------------------------------

__global__ __launch_bounds__(256) void segpool_kernel(const float* __restrict__ p,
                                                      const int* __restrict__ batch,
                                                      float* __restrict__ y, int N, int G) {
    __shared__ float bins[128];
    int t = threadIdx.x;
    if (t < G) bins[t] = 0.f;
    __syncthreads();
    int per = (N + gridDim.x - 1) / gridDim.x;
    int lo = blockIdx.x * per;
    int hi = min(lo + per, N);
    float acc = 0.f;
    int key = -1;
    for (int i = lo + t; i < hi; i += 256) {
        int k = batch[i];
        float v = p[i];
        if (k != key) {
            if (key >= 0) atomicAdd(&bins[key], acc);
            key = k;
            acc = 0.f;
        }
        acc += v;
    }
    if (key >= 0) atomicAdd(&bins[key], acc);
    __syncthreads();
    if (t < G && bins[t] != 0.f) atomicAdd(&y[t], bins[t]);
}

// ---------------------------------------------------------------------------
// Host side
// ---------------------------------------------------------------------------

extern "C" void kernel_launch(void* const* d_in, const int* in_sizes, int n_in,
                              void* d_out, int out_size, void* d_ws, size_t ws_size,
                              hipStream_t stream) {
    const float* x     = (const float*)d_in[0];
    const int*   ei    = (const int*)d_in[1];
    const float* eattr = (const float*)d_in[2];
    const int*   batch = (const int*)d_in[3];
    const float* fw    = (const float*)d_in[16];
    const float* fb    = (const float*)d_in[17];
    float* y = (float*)d_out;

    const int N = in_sizes[0] / DD;     // 50000  (divisible by 16)
    const int E = in_sizes[1] / 2;      // 800000
    const int G = out_size;             // 128

    const int* src = ei;
    const int* dst = ei + E;

    char* ws = (char*)d_ws;
    size_t off = 0;
    auto carve = [&](size_t bytes) {
        char* p = ws + off;
        off += (bytes + 255) & ~(size_t)255;
        return p;
    };
    uint2*  xhb     = (uint2*)carve((size_t)N * 256 * 2);   // bf16 features [N][256]
    uint2*  S0      = (uint2*)carve((size_t)N * 128 * 2);   // shuffled bf16 A (ping)
    uint2*  S1      = (uint2*)carve((size_t)N * 128 * 2);   // shuffled bf16 A (pong)
    unsigned short* Bs = (unsigned short*)carve((size_t)3 * 128 * 256 * 2);
    float2* ae0     = (float2*)carve((size_t)E * 2 * 4);
    float2* ae1     = (float2*)carve((size_t)E * 2 * 4);
    float2* ae2     = (float2*)carve((size_t)E * 2 * 4);
    float*  aiaj    = (float*)carve((size_t)N * 4 * 4);
    int*    row_off = (int*)carve((size_t)(N + 1) * 4);
    int*    cnt     = (int*)carve((size_t)N * 4);
    int*    rank    = (int*)carve((size_t)E * 4);
    int2*   perm2   = (int2*)carve((size_t)E * 8);
    float*  pdots   = (float*)carve((size_t)N * 4);
    int*    bsum    = (int*)carve((size_t)256 * 4);

    const int NB = (N + 1023) / 1024;   // 49 <= 64
    const int Ngroups = N / 16;         // 3125
    const int eb = (E + 255) / 256;     // 3125

    // ---- CSR build: rank (1 atomic pass) -> scans -> perm (no atomics) ----
    hipMemsetAsync(cnt, 0, (size_t)N * 4, stream);
    rank_kernel<<<eb, 256, 0, stream>>>(dst, cnt, rank, E);
    scan1<<<NB, 256, 0, stream>>>(cnt, bsum, N, y, fb);
    scan3<<<NB, 256, 0, stream>>>(cnt, bsum, row_off, N, NB, E);
    perm_kernel<<<eb, 256, 0, stream>>>(src, dst, rank, row_off, perm2, E);

    // ---- fused prep: edge transform (by CSR pos) + pack_a0 + pack_w3 ----
    const int ebA = (N * 32 + 255) / 256;
    const int ebW = (3 * 128 * 64 + 255) / 256;
    prep_fused<<<eb + ebA + ebW, 256, 0, stream>>>(
        eattr, perm2,
        (const float*)d_in[5], (const float*)d_in[6],
        (const float*)d_in[9], (const float*)d_in[10],
        (const float*)d_in[13], (const float*)d_in[14],
        ae0, ae1, ae2, E, eb,
        x, S0, N, ebA,
        (const float*)d_in[4], (const float*)d_in[8], (const float*)d_in[12], Bs);

    // ---- 3 GAT layers ----
    int gemm_blocks = (Ngroups * 2 + 3) / 4;
    int agg_blocks = (N + 3) / 4;
    float2* aes[3] = {ae0, ae1, ae2};
    uint2* Ain[3]  = {S0, S1, S0};
    uint2* Aout[3] = {S1, S0, nullptr};

    for (int l = 0; l < 3; ++l) {
        const float* att  = (const float*)d_in[6 + 4 * l];
        const float* bias = (const float*)d_in[7 + 4 * l];
        const short8* Bl  = (const short8*)(Bs + (size_t)l * 128 * 256);

        gemm_mfma<<<gemm_blocks, 256, 0, stream>>>((const short8*)Ain[l], Bl,
                                                   bias, att, xhb, aiaj, Ngroups);
        aggregate<<<agg_blocks, 256, 0, stream>>>(xhb, aiaj, aes[l], row_off, perm2,
                                                  Aout[l], fw, (l == 2) ? pdots : nullptr, N);
    }

    // ---- pooling ----
    segpool_kernel<<<128, 256, 0, stream>>>(pdots, batch, y, N, G);
}